// Round 1
// baseline (396.831 us; speedup 1.0000x reference)
//
#include <hip/hip_runtime.h>
#include <hip/hip_bf16.h>
#include <float.h>
#include <math.h>

// Problem constants (from reference)
#define NB       4
#define LQ       4096
#define LKV      512
#define DMODEL   512
#define NH       8
#define DH       64
#define LOOKBACK 8
#define KW       (LOOKBACK + 1)
#define SCALE    0.125f   // DH^-0.5 = 1/8

// ---------------------------------------------------------------------------
// Generic fp32 GEMM: C[M,N] = A[M,K] @ W[K,N] + bias[N], optional row zeroing.
// 64x64 tile, BK=16, 256 threads, 4x4 per thread. M%64==0, N%64==0, K%16==0.
// ---------------------------------------------------------------------------
__global__ __launch_bounds__(256) void gemm_bias_kernel(
    const float* __restrict__ A, const float* __restrict__ W,
    const float* __restrict__ bias, float* __restrict__ C,
    int M, int N, int K, const unsigned char* __restrict__ row_mask)
{
    __shared__ float As[16][68];   // A tile transposed [k][m]; stride 68 keeps 16B alignment
    __shared__ float Ws[16][64];   // W tile [k][n]

    const int tid = threadIdx.x;
    const int tx = tid & 15;       // 16 col-threads
    const int ty = tid >> 4;       // 16 row-threads
    const int brow = blockIdx.y * 64;
    const int bcol = blockIdx.x * 64;

    float acc[4][4] = {};

    for (int k0 = 0; k0 < K; k0 += 16) {
        // Load A tile 64(m) x 16(k), store transposed As[k][m]
        #pragma unroll
        for (int i = 0; i < 4; ++i) {
            int e = tid + i * 256;
            int r = e >> 4;        // m in tile
            int c = e & 15;        // k in tile
            As[c][r] = A[(long long)(brow + r) * K + (k0 + c)];
        }
        // Load W tile 16(k) x 64(n)
        #pragma unroll
        for (int i = 0; i < 4; ++i) {
            int e = tid + i * 256;
            int r = e >> 6;        // k in tile
            int c = e & 63;        // n in tile
            Ws[r][c] = W[(long long)(k0 + r) * N + (bcol + c)];
        }
        __syncthreads();

        #pragma unroll
        for (int kk = 0; kk < 16; ++kk) {
            const float4 av = *reinterpret_cast<const float4*>(&As[kk][ty * 4]);
            const float4 bv = *reinterpret_cast<const float4*>(&Ws[kk][tx * 4]);
            const float a[4] = {av.x, av.y, av.z, av.w};
            const float b[4] = {bv.x, bv.y, bv.z, bv.w};
            #pragma unroll
            for (int i = 0; i < 4; ++i)
                #pragma unroll
                for (int j = 0; j < 4; ++j)
                    acc[i][j] = fmaf(a[i], b[j], acc[i][j]);
        }
        __syncthreads();
    }

    #pragma unroll
    for (int i = 0; i < 4; ++i) {
        const int r = brow + ty * 4 + i;
        const bool zero = (row_mask != nullptr) && (row_mask[r] != 0);
        #pragma unroll
        for (int j = 0; j < 4; ++j) {
            const int c = bcol + tx * 4 + j;
            C[(long long)r * N + c] = zero ? 0.0f : (acc[i][j] + bias[c]);
        }
    }
}

// ---------------------------------------------------------------------------
// Windowed attention: one wave per (b,l,h). Lane d (0..63) holds dim d of the
// head. 9-entry gather window from seg_id, shfl-reduced dots, softmax, PV.
// ---------------------------------------------------------------------------
__global__ __launch_bounds__(256) void attn_kernel(
    const float* __restrict__ qh, const float* __restrict__ kh,
    const float* __restrict__ vh, const int* __restrict__ seg_id,
    const unsigned char* __restrict__ kv_mask, float* __restrict__ out)
{
    const int wave = threadIdx.x >> 6;
    const int lane = threadIdx.x & 63;
    const long long item = (long long)blockIdx.x * 4 + wave; // (b*LQ + l)*NH + h
    const int h = (int)(item & (NH - 1));
    const long long bl = item >> 3;           // b*LQ + l
    const int b = (int)(bl >> 12);            // LQ = 2^12

    const float q = qh[bl * DMODEL + h * DH + lane];
    const int seg = seg_id[bl];

    int idxs[KW];
    float scores[KW];
    #pragma unroll
    for (int j = 0; j < KW; ++j) {
        int idx = seg - j;
        idx = idx < 0 ? 0 : (idx > LKV - 1 ? LKV - 1 : idx);
        idxs[j] = idx;
        float p = q * kh[(long long)(b * LKV + idx) * DMODEL + h * DH + lane];
        #pragma unroll
        for (int off = 32; off > 0; off >>= 1) p += __shfl_xor(p, off);
        float s = p * SCALE;
        if (kv_mask[b * LKV + idx]) s = -FLT_MAX;
        scores[j] = s;
    }

    float m = scores[0];
    #pragma unroll
    for (int j = 1; j < KW; ++j) m = fmaxf(m, scores[j]);
    float denom = 0.0f;
    float p[KW];
    #pragma unroll
    for (int j = 0; j < KW; ++j) { p[j] = __expf(scores[j] - m); denom += p[j]; }
    const float inv = 1.0f / denom;

    float o = 0.0f;
    #pragma unroll
    for (int j = 0; j < KW; ++j)
        o = fmaf(p[j], vh[(long long)(b * LKV + idxs[j]) * DMODEL + h * DH + lane], o);

    out[bl * DMODEL + h * DH + lane] = o * inv;
}

extern "C" void kernel_launch(void* const* d_in, const int* in_sizes, int n_in,
                              void* d_out, int out_size, void* d_ws, size_t ws_size,
                              hipStream_t stream) {
    const float*         q          = (const float*)d_in[0];
    const float*         kv_src     = (const float*)d_in[1];
    const int*           seg_id     = (const int*)d_in[2];
    const unsigned char* kv_mask    = (const unsigned char*)d_in[3];
    const unsigned char* q_pad_mask = (const unsigned char*)d_in[4];
    const float*         Wq         = (const float*)d_in[5];
    const float*         bq         = (const float*)d_in[6];
    const float*         Wk         = (const float*)d_in[7];
    const float*         bk         = (const float*)d_in[8];
    const float*         Wv         = (const float*)d_in[9];
    const float*         bv         = (const float*)d_in[10];
    const float*         Wo         = (const float*)d_in[11];
    const float*         bo         = (const float*)d_in[12];
    float* out = (float*)d_out;

    const long long MQ  = (long long)NB * LQ;    // 16384
    const long long MKV = (long long)NB * LKV;   // 2048

    float* ws   = (float*)d_ws;
    float* qh   = ws;                              // MQ  * DMODEL
    float* kh   = qh + MQ * DMODEL;                // MKV * DMODEL
    float* vh   = kh + MKV * DMODEL;               // MKV * DMODEL
    float* attn = vh + MKV * DMODEL;               // MQ  * DMODEL

    dim3 blk(256);
    // Projections
    gemm_bias_kernel<<<dim3(DMODEL / 64, MQ / 64), blk, 0, stream>>>(
        q, Wq, bq, qh, (int)MQ, DMODEL, DMODEL, nullptr);
    gemm_bias_kernel<<<dim3(DMODEL / 64, MKV / 64), blk, 0, stream>>>(
        kv_src, Wk, bk, kh, (int)MKV, DMODEL, DMODEL, nullptr);
    gemm_bias_kernel<<<dim3(DMODEL / 64, MKV / 64), blk, 0, stream>>>(
        kv_src, Wv, bv, vh, (int)MKV, DMODEL, DMODEL, nullptr);

    // Attention: B*LQ*NH items, 4 waves (one item each) per 256-thread block
    const long long items = MQ * NH;               // 131072
    attn_kernel<<<dim3((unsigned)(items / 4)), blk, 0, stream>>>(
        qh, kh, vh, seg_id, kv_mask, attn);

    // Output projection + pad-mask zeroing
    gemm_bias_kernel<<<dim3(DMODEL / 64, MQ / 64), blk, 0, stream>>>(
        attn, Wo, bo, out, (int)MQ, DMODEL, DMODEL, q_pad_mask);
}

// Round 2
// 129.147 us; speedup vs baseline: 3.0727x; 3.0727x over previous
//
#include <hip/hip_runtime.h>
#include <hip/hip_bf16.h>
#include <float.h>

typedef unsigned short u16;
typedef __attribute__((ext_vector_type(8))) short short8;  // 8 bf16 in 4 VGPRs
typedef __attribute__((ext_vector_type(4))) float f32x4;

#define NB       4
#define LQ       4096
#define LKV      512
#define DMODEL   512
#define NH       8
#define DH       64
#define KW       9
#define SCALE    0.125f

__device__ inline float bf2f(u16 v) { return __uint_as_float(((unsigned)v) << 16); }
__device__ inline u16 f2bf(float f) {
    unsigned u = __float_as_uint(f);
    return (u16)((u + 0x7fffu + ((u >> 16) & 1u)) >> 16);   // round-to-nearest-even
}

// ---------------------------------------------------------------------------
// fp32 -> bf16 elementwise (4 elems/thread, grid-stride)
// ---------------------------------------------------------------------------
__global__ __launch_bounds__(256) void cvt_kernel(const float* __restrict__ in,
                                                  u16* __restrict__ out, int n4) {
    int stride = gridDim.x * blockDim.x;
    for (int i = blockIdx.x * blockDim.x + threadIdx.x; i < n4; i += stride) {
        float4 v = ((const float4*)in)[i];
        ushort4 o;
        o.x = f2bf(v.x); o.y = f2bf(v.y); o.z = f2bf(v.z); o.w = f2bf(v.w);
        ((ushort4*)out)[i] = o;
    }
}

// ---------------------------------------------------------------------------
// W[K,N] fp32 -> Wt[N,K] bf16 (512x512), 32x32 LDS tiles
// ---------------------------------------------------------------------------
__global__ __launch_bounds__(256) void transpose_cvt_kernel(const float* __restrict__ W,
                                                            u16* __restrict__ Wt) {
    __shared__ float tile[32][33];
    const int tx = threadIdx.x & 31, ty = threadIdx.x >> 5;   // 32x8
    const int x0 = blockIdx.x * 32, y0 = blockIdx.y * 32;
    #pragma unroll
    for (int i = 0; i < 4; ++i)
        tile[ty + i * 8][tx] = W[(y0 + ty + i * 8) * DMODEL + x0 + tx];
    __syncthreads();
    #pragma unroll
    for (int i = 0; i < 4; ++i)
        Wt[(x0 + ty + i * 8) * DMODEL + y0 + tx] = f2bf(tile[tx][ty + i * 8]);
}

// ---------------------------------------------------------------------------
// bf16 MFMA GEMM: C[M,512] = A[M,K] @ B[K,512] (+bias), B given TRANSPOSED
// as Bt[512,K]. 128x128 tile, BK=32, 4 waves, 16x16x32 MFMA, 4x4 frags/wave.
// LDS staged via global_load_lds(16B) with XOR chunk swizzle (conflict-free
// ds_read_b128). OUT_F32: fp32 out + row_mask zeroing; else bf16 out.
// ---------------------------------------------------------------------------
#define BM 128
#define BN 128
#define BK 32

__device__ inline void gload16(const u16* g, u16* l) {
    __builtin_amdgcn_global_load_lds((const __attribute__((address_space(1))) void*)g,
                                     (__attribute__((address_space(3))) void*)l, 16, 0, 0);
}

template<int OUT_F32>
__global__ __launch_bounds__(256) void gemm_mfma_kernel(
    const u16* __restrict__ A, const u16* __restrict__ Bt,
    const float* __restrict__ bias, void* __restrict__ Cout,
    int M, int K, const unsigned char* __restrict__ row_mask)
{
    __shared__ u16 As[BM * BK];   // 8 KB, [row][chunk^swz]
    __shared__ u16 Bs[BN * BK];   // 8 KB

    const int tid = threadIdx.x;
    const int w = tid >> 6, l = tid & 63;
    const int wr = w >> 1, wc = w & 1;              // wave -> 64x64 quadrant
    const int brow = blockIdx.y * BM, bcol = blockIdx.x * BN;

    // --- staging addressing: wave w stages 16-row chunks {w*2, w*2+1} of A and B
    const int ca   = w * 2;
    const int rsub = l >> 2;                        // row within 16-row chunk
    const int csrc = (l & 3) ^ (rsub & 3);          // swizzled source 16B-chunk
    const u16* gA0 = A  + (long long)(brow + ca * 16 + rsub) * K + csrc * 8;
    const u16* gA1 = gA0 + (long long)16 * K;
    const u16* gB0 = Bt + (long long)(bcol + ca * 16 + rsub) * K + csrc * 8;
    const u16* gB1 = gB0 + (long long)16 * K;
    u16* lA0 = As + (ca * 16) * BK;                 // wave-uniform LDS bases
    u16* lA1 = As + (ca * 16 + 16) * BK;
    u16* lB0 = Bs + (ca * 16) * BK;
    u16* lB1 = Bs + (ca * 16 + 16) * BK;

    // --- fragment addressing
    const int hi = l >> 4, lr = l & 15;
    const int cs = ((hi ^ (lr & 3)) * 8);           // swizzled k-chunk (elems)

    f32x4 acc[4][4] = {};

    for (int k0 = 0; k0 < K; k0 += BK) {
        gload16(gA0 + k0, lA0);
        gload16(gA1 + k0, lA1);
        gload16(gB0 + k0, lB0);
        gload16(gB1 + k0, lB1);
        __syncthreads();                            // drains vmcnt -> LDS ready

        short8 a[4], b[4];
        #pragma unroll
        for (int m = 0; m < 4; ++m)
            a[m] = *(const short8*)&As[(wr * 64 + m * 16 + lr) * BK + cs];
        #pragma unroll
        for (int n = 0; n < 4; ++n)
            b[n] = *(const short8*)&Bs[(wc * 64 + n * 16 + lr) * BK + cs];
        #pragma unroll
        for (int m = 0; m < 4; ++m)
            #pragma unroll
            for (int n = 0; n < 4; ++n)
                acc[m][n] = __builtin_amdgcn_mfma_f32_16x16x32_bf16(a[m], b[n], acc[m][n], 0, 0, 0);
        __syncthreads();                            // protect LDS from next stage
    }

    // --- epilogue: D row=(l>>4)*4+r, col=l&15 (verified gfx950 C/D layout)
    #pragma unroll
    for (int m = 0; m < 4; ++m) {
        #pragma unroll
        for (int n = 0; n < 4; ++n) {
            const int col = bcol + wc * 64 + n * 16 + lr;
            const float bv = bias[col];
            #pragma unroll
            for (int r = 0; r < 4; ++r) {
                const int row = brow + wr * 64 + m * 16 + hi * 4 + r;
                const float v = acc[m][n][r] + bv;
                if (OUT_F32) {
                    ((float*)Cout)[(long long)row * DMODEL + col] =
                        (row_mask != nullptr && row_mask[row]) ? 0.0f : v;
                } else {
                    ((u16*)Cout)[(long long)row * DMODEL + col] = f2bf(v);
                }
            }
        }
    }
}

// ---------------------------------------------------------------------------
// Windowed attention, bf16 in/out. 16 lanes per (b,l,h) item, 4 items/wave.
// Lane handles 4 dims (8B loads). 4-step shfl_xor dot reduce within group.
// ---------------------------------------------------------------------------
__global__ __launch_bounds__(256) void attn_kernel(
    const u16* __restrict__ qh, const u16* __restrict__ kh, const u16* __restrict__ vh,
    const int* __restrict__ seg_id, const unsigned char* __restrict__ kv_mask,
    u16* __restrict__ outb)
{
    const int wave = threadIdx.x >> 6, l = threadIdx.x & 63;
    const int sub = l >> 4, t = l & 15;
    const long long item = (long long)blockIdx.x * 16 + wave * 4 + sub; // (bl)*8 + h
    const int h = (int)(item & 7);
    const long long bl = item >> 3;
    const int b = (int)(bl >> 12);                  // LQ = 2^12

    const long long qoff = bl * DMODEL + h * DH + t * 4;
    const ushort4 qv = *(const ushort4*)&qh[qoff];
    const float q0 = bf2f(qv.x), q1 = bf2f(qv.y), q2 = bf2f(qv.z), q3 = bf2f(qv.w);
    const int seg = seg_id[bl];
    const unsigned char* km = kv_mask + b * LKV;
    const u16* kb = kh + (long long)b * LKV * DMODEL + h * DH + t * 4;
    const u16* vb = vh + (long long)b * LKV * DMODEL + h * DH + t * 4;

    int idxs[KW];
    float sc[KW];
    #pragma unroll
    for (int j = 0; j < KW; ++j) {
        int idx = seg - j;
        idx = idx < 0 ? 0 : (idx > LKV - 1 ? LKV - 1 : idx);
        idxs[j] = idx;
        const ushort4 k4 = *(const ushort4*)&kb[(long long)idx * DMODEL];
        float p = q0 * bf2f(k4.x) + q1 * bf2f(k4.y) + q2 * bf2f(k4.z) + q3 * bf2f(k4.w);
        p += __shfl_xor(p, 1); p += __shfl_xor(p, 2);
        p += __shfl_xor(p, 4); p += __shfl_xor(p, 8);
        float s = p * SCALE;
        if (km[idx]) s = -FLT_MAX;
        sc[j] = s;
    }

    float m = sc[0];
    #pragma unroll
    for (int j = 1; j < KW; ++j) m = fmaxf(m, sc[j]);
    float den = 0.0f, p[KW];
    #pragma unroll
    for (int j = 0; j < KW; ++j) { p[j] = __expf(sc[j] - m); den += p[j]; }
    const float inv = 1.0f / den;

    float o0 = 0, o1 = 0, o2 = 0, o3 = 0;
    #pragma unroll
    for (int j = 0; j < KW; ++j) {
        const ushort4 v4 = *(const ushort4*)&vb[(long long)idxs[j] * DMODEL];
        o0 = fmaf(p[j], bf2f(v4.x), o0); o1 = fmaf(p[j], bf2f(v4.y), o1);
        o2 = fmaf(p[j], bf2f(v4.z), o2); o3 = fmaf(p[j], bf2f(v4.w), o3);
    }
    ushort4 ov;
    ov.x = f2bf(o0 * inv); ov.y = f2bf(o1 * inv);
    ov.z = f2bf(o2 * inv); ov.w = f2bf(o3 * inv);
    *(ushort4*)&outb[qoff] = ov;
}

extern "C" void kernel_launch(void* const* d_in, const int* in_sizes, int n_in,
                              void* d_out, int out_size, void* d_ws, size_t ws_size,
                              hipStream_t stream) {
    const float*         q          = (const float*)d_in[0];
    const float*         kv_src     = (const float*)d_in[1];
    const int*           seg_id     = (const int*)d_in[2];
    const unsigned char* kv_mask    = (const unsigned char*)d_in[3];
    const unsigned char* q_pad_mask = (const unsigned char*)d_in[4];
    const float*         Wq         = (const float*)d_in[5];
    const float*         bq         = (const float*)d_in[6];
    const float*         Wk         = (const float*)d_in[7];
    const float*         bk         = (const float*)d_in[8];
    const float*         Wv         = (const float*)d_in[9];
    const float*         bv         = (const float*)d_in[10];
    const float*         Wo         = (const float*)d_in[11];
    const float*         bo         = (const float*)d_in[12];
    float* out = (float*)d_out;

    const long long MQ  = (long long)NB * LQ;    // 16384
    const long long MKV = (long long)NB * LKV;   // 2048

    // workspace carve-up (all bf16 = u16)
    char* wsb = (char*)d_ws;
    u16* qb   = (u16*)wsb;                         wsb += MQ  * DMODEL * 2;  // 16 MB
    u16* kvb  = (u16*)wsb;                         wsb += MKV * DMODEL * 2;  //  2 MB
    u16* Wqt  = (u16*)wsb;                         wsb += DMODEL * DMODEL * 2;
    u16* Wkt  = (u16*)wsb;                         wsb += DMODEL * DMODEL * 2;
    u16* Wvt  = (u16*)wsb;                         wsb += DMODEL * DMODEL * 2;
    u16* Wot  = (u16*)wsb;                         wsb += DMODEL * DMODEL * 2;
    u16* qhb  = (u16*)wsb;                         wsb += MQ  * DMODEL * 2;  // 16 MB
    u16* khb  = (u16*)wsb;                         wsb += MKV * DMODEL * 2;
    u16* vhb  = (u16*)wsb;                         wsb += MKV * DMODEL * 2;
    u16* atb  = (u16*)wsb;                         wsb += MQ  * DMODEL * 2;  // 16 MB

    dim3 blk(256);
    // convert activations to bf16
    cvt_kernel<<<dim3(2048), blk, 0, stream>>>(q,      qb,  (int)(MQ  * DMODEL / 4));
    cvt_kernel<<<dim3(1024), blk, 0, stream>>>(kv_src, kvb, (int)(MKV * DMODEL / 4));
    // transpose+convert weights
    dim3 tg(DMODEL / 32, DMODEL / 32);
    transpose_cvt_kernel<<<tg, blk, 0, stream>>>(Wq, Wqt);
    transpose_cvt_kernel<<<tg, blk, 0, stream>>>(Wk, Wkt);
    transpose_cvt_kernel<<<tg, blk, 0, stream>>>(Wv, Wvt);
    transpose_cvt_kernel<<<tg, blk, 0, stream>>>(Wo, Wot);

    // projections (bf16 MFMA)
    gemm_mfma_kernel<0><<<dim3(DMODEL / BN, MQ / BM),  blk, 0, stream>>>(
        qb,  Wqt, bq, qhb, (int)MQ,  DMODEL, nullptr);
    gemm_mfma_kernel<0><<<dim3(DMODEL / BN, MKV / BM), blk, 0, stream>>>(
        kvb, Wkt, bk, khb, (int)MKV, DMODEL, nullptr);
    gemm_mfma_kernel<0><<<dim3(DMODEL / BN, MKV / BM), blk, 0, stream>>>(
        kvb, Wvt, bv, vhb, (int)MKV, DMODEL, nullptr);

    // windowed attention: MQ*NH items, 16 per block
    attn_kernel<<<dim3((unsigned)(MQ * NH / 16)), blk, 0, stream>>>(
        qhb, khb, vhb, seg_id, kv_mask, atb);

    // output projection + pad-mask zeroing (fp32 out)
    gemm_mfma_kernel<1><<<dim3(DMODEL / BN, MQ / BM),  blk, 0, stream>>>(
        atb, Wot, bo, out, (int)MQ, DMODEL, q_pad_mask);
}

// Round 3
// 107.880 us; speedup vs baseline: 3.6784x; 1.1971x over previous
//
#include <hip/hip_runtime.h>
#include <hip/hip_bf16.h>
#include <float.h>

typedef unsigned short u16;
typedef __attribute__((ext_vector_type(8))) short short8;  // 8 bf16 in 4 VGPRs
typedef __attribute__((ext_vector_type(4))) float f32x4;

#define NB       4
#define LQ       4096
#define LKV      512
#define DMODEL   512
#define NH       8
#define DH       64
#define KW       9
#define SCALE    0.125f

#define BM 128
#define BN 128
#define BK 32

__device__ inline float bf2f(u16 v) { return __uint_as_float(((unsigned)v) << 16); }
__device__ inline u16 f2bf(float f) {
    unsigned u = __float_as_uint(f);
    return (u16)((u + 0x7fffu + ((u >> 16) & 1u)) >> 16);   // RNE
}
__device__ inline void gload16(const u16* g, u16* l) {
    __builtin_amdgcn_global_load_lds((const __attribute__((address_space(1))) void*)g,
                                     (__attribute__((address_space(3))) void*)l, 16, 0, 0);
}

// ---------------------------------------------------------------------------
// fused fp32->bf16 convert for q and kv_src (one launch)
// ---------------------------------------------------------------------------
__global__ __launch_bounds__(256) void cvt2_kernel(
    const float* __restrict__ a, u16* __restrict__ oa, int n4a,
    const float* __restrict__ b, u16* __restrict__ ob, int n4b)
{
    const int stride = gridDim.x * blockDim.x;
    const int total = n4a + n4b;
    for (int i = blockIdx.x * blockDim.x + threadIdx.x; i < total; i += stride) {
        const float4 v = (i < n4a) ? ((const float4*)a)[i] : ((const float4*)b)[i - n4a];
        ushort4 o;
        o.x = f2bf(v.x); o.y = f2bf(v.y); o.z = f2bf(v.z); o.w = f2bf(v.w);
        if (i < n4a) ((ushort4*)oa)[i] = o; else ((ushort4*)ob)[i - n4a] = o;
    }
}

// ---------------------------------------------------------------------------
// all 4 weight transposes in one launch (blockIdx.z selects matrix)
// Wq -> Wqt[512][512]; Wk -> Wkvt rows 0-511; Wv -> Wkvt rows 512-1023; Wo -> Wot
// ---------------------------------------------------------------------------
__global__ __launch_bounds__(256) void transpose4_kernel(
    const float* __restrict__ Wq, const float* __restrict__ Wk,
    const float* __restrict__ Wv, const float* __restrict__ Wo,
    u16* __restrict__ Wqt, u16* __restrict__ Wkvt, u16* __restrict__ Wot)
{
    __shared__ float tile[32][33];
    const int z = blockIdx.z;
    const float* src = (z == 0) ? Wq : (z == 1) ? Wk : (z == 2) ? Wv : Wo;
    u16* dst = (z == 0) ? Wqt : (z == 3) ? Wot : Wkvt;
    const int roff = (z == 2) ? DMODEL : 0;

    const int tx = threadIdx.x & 31, ty = threadIdx.x >> 5;   // 32x8
    const int x0 = blockIdx.x * 32, y0 = blockIdx.y * 32;
    #pragma unroll
    for (int i = 0; i < 4; ++i)
        tile[ty + i * 8][tx] = src[(y0 + ty + i * 8) * DMODEL + x0 + tx];
    __syncthreads();
    #pragma unroll
    for (int i = 0; i < 4; ++i)
        dst[(long long)(roff + x0 + ty + i * 8) * DMODEL + y0 + tx] = f2bf(tile[tx][ty + i * 8]);
}

// ---------------------------------------------------------------------------
// Generic bf16 MFMA GEMM: C[M,N] = A[M,K] @ Bt[N,K]^T (+ split bias)
// 128x128 tile, BK=32, 4 waves, 16x16x32 MFMA. OUT_F32: fp32 out + row mask.
// ---------------------------------------------------------------------------
template<int OUT_F32>
__global__ __launch_bounds__(256) void gemm_mfma_kernel(
    const u16* __restrict__ A, const u16* __restrict__ Bt,
    const float* __restrict__ bias0, const float* __restrict__ bias1, int nsplit,
    void* __restrict__ Cout, int M, int N, int K,
    const unsigned char* __restrict__ row_mask)
{
    __shared__ u16 As[BM * BK];
    __shared__ u16 Bs[BN * BK];

    const int tid = threadIdx.x;
    const int w = tid >> 6, l = tid & 63;
    const int wr = w >> 1, wc = w & 1;
    const int brow = blockIdx.y * BM, bcol = blockIdx.x * BN;

    const int ca   = w * 2;
    const int rsub = l >> 2;
    const int csrc = (l & 3) ^ (rsub & 3);
    const u16* gA0 = A  + (long long)(brow + ca * 16 + rsub) * K + csrc * 8;
    const u16* gA1 = gA0 + (long long)16 * K;
    const u16* gB0 = Bt + (long long)(bcol + ca * 16 + rsub) * K + csrc * 8;
    const u16* gB1 = gB0 + (long long)16 * K;
    u16* lA0 = As + (ca * 16) * BK;
    u16* lA1 = As + (ca * 16 + 16) * BK;
    u16* lB0 = Bs + (ca * 16) * BK;
    u16* lB1 = Bs + (ca * 16 + 16) * BK;

    const int hi = l >> 4, lr = l & 15;
    const int cs = ((hi ^ (lr & 3)) * 8);

    f32x4 acc[4][4] = {};

    for (int k0 = 0; k0 < K; k0 += BK) {
        gload16(gA0 + k0, lA0);
        gload16(gA1 + k0, lA1);
        gload16(gB0 + k0, lB0);
        gload16(gB1 + k0, lB1);
        __syncthreads();

        short8 a[4], b[4];
        #pragma unroll
        for (int m = 0; m < 4; ++m)
            a[m] = *(const short8*)&As[(wr * 64 + m * 16 + lr) * BK + cs];
        #pragma unroll
        for (int n = 0; n < 4; ++n)
            b[n] = *(const short8*)&Bs[(wc * 64 + n * 16 + lr) * BK + cs];
        #pragma unroll
        for (int m = 0; m < 4; ++m)
            #pragma unroll
            for (int n = 0; n < 4; ++n)
                acc[m][n] = __builtin_amdgcn_mfma_f32_16x16x32_bf16(a[m], b[n], acc[m][n], 0, 0, 0);
        __syncthreads();
    }

    #pragma unroll
    for (int m = 0; m < 4; ++m) {
        #pragma unroll
        for (int n = 0; n < 4; ++n) {
            const int col = bcol + wc * 64 + n * 16 + lr;
            const float bv = (col < nsplit) ? bias0[col] : bias1[col - nsplit];
            #pragma unroll
            for (int r = 0; r < 4; ++r) {
                const int row = brow + wr * 64 + m * 16 + hi * 4 + r;
                const float v = acc[m][n][r] + bv;
                if (OUT_F32) {
                    ((float*)Cout)[(long long)row * N + col] =
                        (row_mask != nullptr && row_mask[row]) ? 0.0f : v;
                } else {
                    ((u16*)Cout)[(long long)row * N + col] = f2bf(v);
                }
            }
        }
    }
}

// ---------------------------------------------------------------------------
// FUSED Q-projection + windowed attention.
// GEMM phase: qh_tile[128 rows][128 cols = 2 heads] via MFMA (as above).
// Epilogue: acc+bias -> bf16 -> swizzled LDS tile; then 1 thread = 1 (row,head)
// item: thread-local 9-window attention vs K/V in khv [MKV][1024] (L2-resident),
// writes atb[row][head*64+d] bf16.
// ---------------------------------------------------------------------------
__global__ __launch_bounds__(256) void qproj_attn_kernel(
    const u16* __restrict__ A, const u16* __restrict__ Bt,
    const float* __restrict__ bias, const u16* __restrict__ khv,
    const int* __restrict__ seg_id, const unsigned char* __restrict__ kv_mask,
    u16* __restrict__ atb)
{
    __shared__ u16 As[BM * BK];
    __shared__ u16 Bs[BN * BK];
    __shared__ u16 qt[BM * BN];        // 32 KB, XOR-swizzled 16B chunks

    const int tid = threadIdx.x;
    const int w = tid >> 6, l = tid & 63;
    const int wr = w >> 1, wc = w & 1;
    const int brow = blockIdx.y * BM, bcol = blockIdx.x * BN;
    const int K = DMODEL;

    const int ca   = w * 2;
    const int rsub = l >> 2;
    const int csrc = (l & 3) ^ (rsub & 3);
    const u16* gA0 = A  + (long long)(brow + ca * 16 + rsub) * K + csrc * 8;
    const u16* gA1 = gA0 + (long long)16 * K;
    const u16* gB0 = Bt + (long long)(bcol + ca * 16 + rsub) * K + csrc * 8;
    const u16* gB1 = gB0 + (long long)16 * K;
    u16* lA0 = As + (ca * 16) * BK;
    u16* lA1 = As + (ca * 16 + 16) * BK;
    u16* lB0 = Bs + (ca * 16) * BK;
    u16* lB1 = Bs + (ca * 16 + 16) * BK;

    const int hi = l >> 4, lr = l & 15;
    const int cs = ((hi ^ (lr & 3)) * 8);

    f32x4 acc[4][4] = {};

    for (int k0 = 0; k0 < K; k0 += BK) {
        gload16(gA0 + k0, lA0);
        gload16(gA1 + k0, lA1);
        gload16(gB0 + k0, lB0);
        gload16(gB1 + k0, lB1);
        __syncthreads();

        short8 a[4], b[4];
        #pragma unroll
        for (int m = 0; m < 4; ++m)
            a[m] = *(const short8*)&As[(wr * 64 + m * 16 + lr) * BK + cs];
        #pragma unroll
        for (int n = 0; n < 4; ++n)
            b[n] = *(const short8*)&Bs[(wc * 64 + n * 16 + lr) * BK + cs];
        #pragma unroll
        for (int m = 0; m < 4; ++m)
            #pragma unroll
            for (int n = 0; n < 4; ++n)
                acc[m][n] = __builtin_amdgcn_mfma_f32_16x16x32_bf16(a[m], b[n], acc[m][n], 0, 0, 0);
        __syncthreads();
    }

    // ---- stash qh tile (with bias, bf16) into swizzled LDS ----
    #pragma unroll
    for (int m = 0; m < 4; ++m) {
        #pragma unroll
        for (int n = 0; n < 4; ++n) {
            const int col = wc * 64 + n * 16 + lr;               // local col
            const float bv = bias[bcol + col];
            const int g = col >> 3;
            #pragma unroll
            for (int r = 0; r < 4; ++r) {
                const int row = wr * 64 + m * 16 + hi * 4 + r;   // local row
                qt[row * BN + ((g ^ (row & 7)) << 3) + (col & 7)] =
                    f2bf(acc[m][n][r] + bv);
            }
        }
    }
    __syncthreads();

    // ---- per-thread windowed attention: item = (row, head-half) ----
    const int row = tid >> 1;                 // 0..127 local row
    const int h2  = tid & 1;                  // which of the tile's 2 heads
    const long long bl = brow + row;
    const int b = (int)(bl >> 12);            // LQ = 2^12
    const int head = (bcol >> 6) + h2;        // global head 0..7
    const int seg = seg_id[bl];
    const unsigned char* km = kv_mask + b * LKV;
    const u16* kvb = khv + (long long)b * LKV * 1024;

    // q row for this head: 64 bf16 from LDS -> fp32
    float qf[64];
    #pragma unroll
    for (int c = 0; c < 8; ++c) {
        const int g = h2 * 8 + c;
        const short8 v = *(const short8*)&qt[row * BN + ((g ^ (row & 7)) << 3)];
        #pragma unroll
        for (int e = 0; e < 8; ++e) qf[c * 8 + e] = bf2f((u16)v[e]);
    }

    int idxs[KW];
    float sc[KW];
    #pragma unroll
    for (int j = 0; j < KW; ++j) {
        int idx = seg - j;
        idx = idx < 0 ? 0 : (idx > LKV - 1 ? LKV - 1 : idx);
        idxs[j] = idx;
        const u16* kp = kvb + (long long)idx * 1024 + head * DH;
        float dot = 0.0f;
        #pragma unroll
        for (int c = 0; c < 8; ++c) {
            const short8 k8 = *(const short8*)&kp[c * 8];
            #pragma unroll
            for (int e = 0; e < 8; ++e)
                dot = fmaf(qf[c * 8 + e], bf2f((u16)k8[e]), dot);
        }
        float s = dot * SCALE;
        if (km[idx]) s = -FLT_MAX;
        sc[j] = s;
    }

    float mx = sc[0];
    #pragma unroll
    for (int j = 1; j < KW; ++j) mx = fmaxf(mx, sc[j]);
    float den = 0.0f, p[KW];
    #pragma unroll
    for (int j = 0; j < KW; ++j) { p[j] = __expf(sc[j] - mx); den += p[j]; }
    const float inv = 1.0f / den;

    float o[64];
    #pragma unroll
    for (int d = 0; d < 64; ++d) o[d] = 0.0f;
    #pragma unroll
    for (int j = 0; j < KW; ++j) {
        const u16* vp = kvb + (long long)idxs[j] * 1024 + DMODEL + head * DH;
        const float pj = p[j];
        #pragma unroll
        for (int c = 0; c < 8; ++c) {
            const short8 v8 = *(const short8*)&vp[c * 8];
            #pragma unroll
            for (int e = 0; e < 8; ++e)
                o[c * 8 + e] = fmaf(pj, bf2f((u16)v8[e]), o[c * 8 + e]);
        }
    }

    u16* op = atb + bl * DMODEL + head * DH;
    #pragma unroll
    for (int c = 0; c < 8; ++c) {
        short8 ov;
        #pragma unroll
        for (int e = 0; e < 8; ++e) ov[e] = (short)f2bf(o[c * 8 + e] * inv);
        *(short8*)&op[c * 8] = ov;
    }
}

extern "C" void kernel_launch(void* const* d_in, const int* in_sizes, int n_in,
                              void* d_out, int out_size, void* d_ws, size_t ws_size,
                              hipStream_t stream) {
    const float*         q          = (const float*)d_in[0];
    const float*         kv_src     = (const float*)d_in[1];
    const int*           seg_id     = (const int*)d_in[2];
    const unsigned char* kv_mask    = (const unsigned char*)d_in[3];
    const unsigned char* q_pad_mask = (const unsigned char*)d_in[4];
    const float*         Wq         = (const float*)d_in[5];
    const float*         bq         = (const float*)d_in[6];
    const float*         Wk         = (const float*)d_in[7];
    const float*         bk         = (const float*)d_in[8];
    const float*         Wv         = (const float*)d_in[9];
    const float*         bv         = (const float*)d_in[10];
    const float*         Wo         = (const float*)d_in[11];
    const float*         bo         = (const float*)d_in[12];
    float* out = (float*)d_out;

    const long long MQ  = (long long)NB * LQ;    // 16384
    const long long MKV = (long long)NB * LKV;   // 2048

    char* wsb = (char*)d_ws;
    u16* qb   = (u16*)wsb;  wsb += MQ  * DMODEL * 2;          // 16 MB
    u16* kvb  = (u16*)wsb;  wsb += MKV * DMODEL * 2;          //  2 MB
    u16* Wqt  = (u16*)wsb;  wsb += DMODEL * DMODEL * 2;       // 0.5 MB
    u16* Wkvt = (u16*)wsb;  wsb += 2 * DMODEL * DMODEL * 2;   //  1 MB
    u16* Wot  = (u16*)wsb;  wsb += DMODEL * DMODEL * 2;       // 0.5 MB
    u16* khv  = (u16*)wsb;  wsb += MKV * 2 * DMODEL * 2;      //  4 MB
    u16* atb  = (u16*)wsb;  wsb += MQ  * DMODEL * 2;          // 16 MB

    dim3 blk(256);

    cvt2_kernel<<<dim3(2048), blk, 0, stream>>>(
        q, qb, (int)(MQ * DMODEL / 4), kv_src, kvb, (int)(MKV * DMODEL / 4));

    transpose4_kernel<<<dim3(DMODEL / 32, DMODEL / 32, 4), blk, 0, stream>>>(
        Wq, Wk, Wv, Wo, Wqt, Wkvt, Wot);

    // fused K+V projection: C[MKV][1024] (cols 0-511 = K, 512-1023 = V)
    gemm_mfma_kernel<0><<<dim3(2 * DMODEL / BN, MKV / BM), blk, 0, stream>>>(
        kvb, Wkvt, bk, bv, DMODEL, khv, (int)MKV, 2 * DMODEL, DMODEL, nullptr);

    // fused Q projection + windowed attention -> atb
    qproj_attn_kernel<<<dim3(DMODEL / BN, MQ / BM), blk, 0, stream>>>(
        qb, Wqt, bq, khv, seg_id, kv_mask, atb);

    // output projection + pad-mask zeroing (fp32 out)
    gemm_mfma_kernel<1><<<dim3(DMODEL / BN, MQ / BM), blk, 0, stream>>>(
        atb, Wot, bo, bo, DMODEL, out, (int)MQ, DMODEL, DMODEL, q_pad_mask);
}

// Round 4
// 101.225 us; speedup vs baseline: 3.9203x; 1.0658x over previous
//
#include <hip/hip_runtime.h>
#include <hip/hip_bf16.h>
#include <float.h>

typedef unsigned short u16;
typedef __attribute__((ext_vector_type(8))) short short8;  // 8 bf16 in 4 VGPRs
typedef __attribute__((ext_vector_type(4))) float f32x4;

#define NB       4
#define LQ       4096
#define LKV      512
#define DMODEL   512
#define NH       8
#define DH       64
#define KW       9
#define SCALE    0.125f

#define BM 64
#define BN 128
#define BK 32

__device__ inline float bf2f(u16 v) { return __uint_as_float(((unsigned)v) << 16); }
__device__ inline u16 f2bf(float f) {
    unsigned u = __float_as_uint(f);
    return (u16)((u + 0x7fffu + ((u >> 16) & 1u)) >> 16);   // RNE
}
__device__ inline void gload16(const u16* g, u16* l) {
    __builtin_amdgcn_global_load_lds((const __attribute__((address_space(1))) void*)g,
                                     (__attribute__((address_space(3))) void*)l, 16, 0, 0);
}

// ---------------------------------------------------------------------------
// fused fp32->bf16 convert for q and kv_src (one launch)
// ---------------------------------------------------------------------------
__global__ __launch_bounds__(256) void cvt2_kernel(
    const float* __restrict__ a, u16* __restrict__ oa, int n4a,
    const float* __restrict__ b, u16* __restrict__ ob, int n4b)
{
    const int stride = gridDim.x * blockDim.x;
    const int total = n4a + n4b;
    for (int i = blockIdx.x * blockDim.x + threadIdx.x; i < total; i += stride) {
        const float4 v = (i < n4a) ? ((const float4*)a)[i] : ((const float4*)b)[i - n4a];
        ushort4 o;
        o.x = f2bf(v.x); o.y = f2bf(v.y); o.z = f2bf(v.z); o.w = f2bf(v.w);
        if (i < n4a) ((ushort4*)oa)[i] = o; else ((ushort4*)ob)[i - n4a] = o;
    }
}

// ---------------------------------------------------------------------------
// all 4 weight transposes in one launch (blockIdx.z selects matrix)
// ---------------------------------------------------------------------------
__global__ __launch_bounds__(256) void transpose4_kernel(
    const float* __restrict__ Wq, const float* __restrict__ Wk,
    const float* __restrict__ Wv, const float* __restrict__ Wo,
    u16* __restrict__ Wqt, u16* __restrict__ Wkvt, u16* __restrict__ Wot)
{
    __shared__ float tile[32][33];
    const int z = blockIdx.z;
    const float* src = (z == 0) ? Wq : (z == 1) ? Wk : (z == 2) ? Wv : Wo;
    u16* dst = (z == 0) ? Wqt : (z == 3) ? Wot : Wkvt;
    const int roff = (z == 2) ? DMODEL : 0;

    const int tx = threadIdx.x & 31, ty = threadIdx.x >> 5;   // 32x8
    const int x0 = blockIdx.x * 32, y0 = blockIdx.y * 32;
    #pragma unroll
    for (int i = 0; i < 4; ++i)
        tile[ty + i * 8][tx] = src[(y0 + ty + i * 8) * DMODEL + x0 + tx];
    __syncthreads();
    #pragma unroll
    for (int i = 0; i < 4; ++i)
        dst[(long long)(roff + x0 + ty + i * 8) * DMODEL + y0 + tx] = f2bf(tile[tx][ty + i * 8]);
}

// ---------------------------------------------------------------------------
// bf16 MFMA GEMM, 64x128 tile, BK=32, 4 waves (each 32x64, acc[2][4]).
// C[M,N] = A[M,K] @ Bt[N,K]^T + split bias. OUT_F32: fp32 out + row mask.
// ---------------------------------------------------------------------------
template<int OUT_F32>
__global__ __launch_bounds__(256, 4) void gemm64_kernel(
    const u16* __restrict__ A, const u16* __restrict__ Bt,
    const float* __restrict__ bias0, const float* __restrict__ bias1, int nsplit,
    void* __restrict__ Cout, int M, int N, int K,
    const unsigned char* __restrict__ row_mask)
{
    __shared__ u16 As[BM * BK];   // 4 KB
    __shared__ u16 Bs[BN * BK];   // 8 KB

    const int tid = threadIdx.x;
    const int w = tid >> 6, l = tid & 63;
    const int wr = w >> 1, wc = w & 1;
    const int brow = blockIdx.y * BM, bcol = blockIdx.x * BN;

    // staging: wave w -> A 16-row chunk w; B 16-row chunks 2w, 2w+1
    const int rsub = l >> 2;
    const int csrc = (l & 3) ^ (rsub & 3);
    const u16* gA  = A  + (long long)(brow + w * 16 + rsub) * K + csrc * 8;
    const u16* gB0 = Bt + (long long)(bcol + w * 32 + rsub) * K + csrc * 8;
    const u16* gB1 = gB0 + (long long)16 * K;
    u16* lA  = As + (w * 16) * BK;
    u16* lB0 = Bs + (w * 32) * BK;
    u16* lB1 = Bs + (w * 32 + 16) * BK;

    const int hi = l >> 4, lr = l & 15;
    const int cs = ((hi ^ (lr & 3)) * 8);

    f32x4 acc[2][4] = {};

    for (int k0 = 0; k0 < K; k0 += BK) {
        gload16(gA  + k0, lA);
        gload16(gB0 + k0, lB0);
        gload16(gB1 + k0, lB1);
        __syncthreads();

        short8 a[2], b[4];
        #pragma unroll
        for (int m = 0; m < 2; ++m)
            a[m] = *(const short8*)&As[(wr * 32 + m * 16 + lr) * BK + cs];
        #pragma unroll
        for (int n = 0; n < 4; ++n)
            b[n] = *(const short8*)&Bs[(wc * 64 + n * 16 + lr) * BK + cs];
        #pragma unroll
        for (int m = 0; m < 2; ++m)
            #pragma unroll
            for (int n = 0; n < 4; ++n)
                acc[m][n] = __builtin_amdgcn_mfma_f32_16x16x32_bf16(a[m], b[n], acc[m][n], 0, 0, 0);
        __syncthreads();
    }

    #pragma unroll
    for (int m = 0; m < 2; ++m) {
        #pragma unroll
        for (int n = 0; n < 4; ++n) {
            const int col = bcol + wc * 64 + n * 16 + lr;
            const float bv = (col < nsplit) ? bias0[col] : bias1[col - nsplit];
            #pragma unroll
            for (int r = 0; r < 4; ++r) {
                const int row = brow + wr * 32 + m * 16 + hi * 4 + r;
                const float v = acc[m][n][r] + bv;
                if (OUT_F32) {
                    ((float*)Cout)[(long long)row * N + col] =
                        (row_mask != nullptr && row_mask[row]) ? 0.0f : v;
                } else {
                    ((u16*)Cout)[(long long)row * N + col] = f2bf(v);
                }
            }
        }
    }
}

// ---------------------------------------------------------------------------
// FUSED Q-projection (64x128 tile = 64 rows x 2 heads) + windowed attention.
// Epilogue: acc+bias -> bf16 swizzled LDS qt[64][128]; then 2 threads per
// (row,head) item, 32 dims each, one shfl_xor(1) closes each dot.
// ---------------------------------------------------------------------------
__global__ __launch_bounds__(256, 4) void qproj_attn_kernel(
    const u16* __restrict__ A, const u16* __restrict__ Bt,
    const float* __restrict__ bias, const u16* __restrict__ khv,
    const int* __restrict__ seg_id, const unsigned char* __restrict__ kv_mask,
    u16* __restrict__ atb)
{
    __shared__ u16 As[BM * BK];     // 4 KB
    __shared__ u16 Bs[BN * BK];     // 8 KB
    __shared__ u16 qt[BM * BN];     // 16 KB, XOR-swizzled 16B chunks

    const int tid = threadIdx.x;
    const int w = tid >> 6, l = tid & 63;
    const int wr = w >> 1, wc = w & 1;
    const int brow = blockIdx.y * BM, bcol = blockIdx.x * BN;
    const int K = DMODEL;

    const int rsub = l >> 2;
    const int csrc = (l & 3) ^ (rsub & 3);
    const u16* gA  = A  + (long long)(brow + w * 16 + rsub) * K + csrc * 8;
    const u16* gB0 = Bt + (long long)(bcol + w * 32 + rsub) * K + csrc * 8;
    const u16* gB1 = gB0 + (long long)16 * K;
    u16* lA  = As + (w * 16) * BK;
    u16* lB0 = Bs + (w * 32) * BK;
    u16* lB1 = Bs + (w * 32 + 16) * BK;

    const int hi = l >> 4, lr = l & 15;
    const int cs = ((hi ^ (lr & 3)) * 8);

    f32x4 acc[2][4] = {};

    for (int k0 = 0; k0 < K; k0 += BK) {
        gload16(gA  + k0, lA);
        gload16(gB0 + k0, lB0);
        gload16(gB1 + k0, lB1);
        __syncthreads();

        short8 a[2], b[4];
        #pragma unroll
        for (int m = 0; m < 2; ++m)
            a[m] = *(const short8*)&As[(wr * 32 + m * 16 + lr) * BK + cs];
        #pragma unroll
        for (int n = 0; n < 4; ++n)
            b[n] = *(const short8*)&Bs[(wc * 64 + n * 16 + lr) * BK + cs];
        #pragma unroll
        for (int m = 0; m < 2; ++m)
            #pragma unroll
            for (int n = 0; n < 4; ++n)
                acc[m][n] = __builtin_amdgcn_mfma_f32_16x16x32_bf16(a[m], b[n], acc[m][n], 0, 0, 0);
        __syncthreads();
    }

    // stash qh tile (+bias, bf16) into swizzled LDS
    #pragma unroll
    for (int m = 0; m < 2; ++m) {
        #pragma unroll
        for (int n = 0; n < 4; ++n) {
            const int col = wc * 64 + n * 16 + lr;
            const float bv = bias[bcol + col];
            const int g = col >> 3;
            #pragma unroll
            for (int r = 0; r < 4; ++r) {
                const int row = wr * 32 + m * 16 + hi * 4 + r;
                qt[row * BN + ((g ^ (row & 7)) << 3) + (col & 7)] =
                    f2bf(acc[m][n][r] + bv);
            }
        }
    }
    __syncthreads();

    // per-thread attention: 2 threads per (row, head) item, 32 dims each
    const int row  = tid >> 2;                // 0..63 local row
    const int h2   = (tid >> 1) & 1;          // head within tile
    const int half = tid & 1;                 // dim half (0: d0-31, 1: d32-63)
    const long long bl = brow + row;
    const int b = (int)(bl >> 12);            // LQ = 2^12
    const int head = (bcol >> 6) + h2;        // global head
    const int seg = seg_id[bl];
    const unsigned char* km = kv_mask + b * LKV;
    const u16* kvb = khv + (long long)b * LKV * 1024;

    // q: 32 dims packed bf16 (4x short8) from swizzled qt
    short8 q8[4];
    #pragma unroll
    for (int c = 0; c < 4; ++c) {
        const int g = h2 * 8 + half * 4 + c;
        q8[c] = *(const short8*)&qt[row * BN + ((g ^ (row & 7)) << 3)];
    }

    int idxs[KW];
    float sc[KW];
    #pragma unroll
    for (int j = 0; j < KW; ++j) {
        int idx = seg - j;
        idx = idx < 0 ? 0 : (idx > LKV - 1 ? LKV - 1 : idx);
        idxs[j] = idx;
        const u16* kp = kvb + (long long)idx * 1024 + head * DH + half * 32;
        float dot = 0.0f;
        #pragma unroll
        for (int c = 0; c < 4; ++c) {
            const short8 k8 = *(const short8*)&kp[c * 8];
            #pragma unroll
            for (int e = 0; e < 8; ++e)
                dot = fmaf(bf2f((u16)q8[c][e]), bf2f((u16)k8[e]), dot);
        }
        dot += __shfl_xor(dot, 1);            // combine the two 32-dim halves
        float s = dot * SCALE;
        if (km[idx]) s = -FLT_MAX;
        sc[j] = s;
    }

    float mx = sc[0];
    #pragma unroll
    for (int j = 1; j < KW; ++j) mx = fmaxf(mx, sc[j]);
    float den = 0.0f;
    #pragma unroll
    for (int j = 0; j < KW; ++j) { sc[j] = __expf(sc[j] - mx); den += sc[j]; }
    const float inv = 1.0f / den;

    float o[32];
    #pragma unroll
    for (int d = 0; d < 32; ++d) o[d] = 0.0f;
    #pragma unroll
    for (int j = 0; j < KW; ++j) {
        const u16* vp = kvb + (long long)idxs[j] * 1024 + DMODEL + head * DH + half * 32;
        const float pj = sc[j];
        #pragma unroll
        for (int c = 0; c < 4; ++c) {
            const short8 v8 = *(const short8*)&vp[c * 8];
            #pragma unroll
            for (int e = 0; e < 8; ++e)
                o[c * 8 + e] = fmaf(pj, bf2f((u16)v8[e]), o[c * 8 + e]);
        }
    }

    u16* op = atb + bl * DMODEL + head * DH + half * 32;
    #pragma unroll
    for (int c = 0; c < 4; ++c) {
        short8 ov;
        #pragma unroll
        for (int e = 0; e < 8; ++e) ov[e] = (short)f2bf(o[c * 8 + e] * inv);
        *(short8*)&op[c * 8] = ov;
    }
}

extern "C" void kernel_launch(void* const* d_in, const int* in_sizes, int n_in,
                              void* d_out, int out_size, void* d_ws, size_t ws_size,
                              hipStream_t stream) {
    const float*         q          = (const float*)d_in[0];
    const float*         kv_src     = (const float*)d_in[1];
    const int*           seg_id     = (const int*)d_in[2];
    const unsigned char* kv_mask    = (const unsigned char*)d_in[3];
    const unsigned char* q_pad_mask = (const unsigned char*)d_in[4];
    const float*         Wq         = (const float*)d_in[5];
    const float*         bq         = (const float*)d_in[6];
    const float*         Wk         = (const float*)d_in[7];
    const float*         bk         = (const float*)d_in[8];
    const float*         Wv         = (const float*)d_in[9];
    const float*         bv         = (const float*)d_in[10];
    const float*         Wo         = (const float*)d_in[11];
    const float*         bo         = (const float*)d_in[12];
    float* out = (float*)d_out;

    const long long MQ  = (long long)NB * LQ;    // 16384
    const long long MKV = (long long)NB * LKV;   // 2048

    char* wsb = (char*)d_ws;
    u16* qb   = (u16*)wsb;  wsb += MQ  * DMODEL * 2;          // 16 MB
    u16* kvb  = (u16*)wsb;  wsb += MKV * DMODEL * 2;          //  2 MB
    u16* Wqt  = (u16*)wsb;  wsb += DMODEL * DMODEL * 2;       // 0.5 MB
    u16* Wkvt = (u16*)wsb;  wsb += 2 * DMODEL * DMODEL * 2;   //  1 MB
    u16* Wot  = (u16*)wsb;  wsb += DMODEL * DMODEL * 2;       // 0.5 MB
    u16* khv  = (u16*)wsb;  wsb += MKV * 2 * DMODEL * 2;      //  4 MB
    u16* atb  = (u16*)wsb;  wsb += MQ  * DMODEL * 2;          // 16 MB

    dim3 blk(256);

    cvt2_kernel<<<dim3(2048), blk, 0, stream>>>(
        q, qb, (int)(MQ * DMODEL / 4), kv_src, kvb, (int)(MKV * DMODEL / 4));

    transpose4_kernel<<<dim3(DMODEL / 32, DMODEL / 32, 4), blk, 0, stream>>>(
        Wq, Wk, Wv, Wo, Wqt, Wkvt, Wot);

    // fused K+V projection: C[MKV][1024] (cols 0-511 = K, 512-1023 = V)
    gemm64_kernel<0><<<dim3(2 * DMODEL / BN, MKV / BM), blk, 0, stream>>>(
        kvb, Wkvt, bk, bv, DMODEL, khv, (int)MKV, 2 * DMODEL, DMODEL, nullptr);

    // fused Q projection + windowed attention -> atb  (1024 blocks)
    qproj_attn_kernel<<<dim3(DMODEL / BN, MQ / BM), blk, 0, stream>>>(
        qb, Wqt, bq, khv, seg_id, kv_mask, atb);

    // output projection + pad-mask zeroing (fp32 out)  (1024 blocks)
    gemm64_kernel<1><<<dim3(DMODEL / BN, MQ / BM), blk, 0, stream>>>(
        atb, Wot, bo, bo, DMODEL, out, (int)MQ, DMODEL, DMODEL, q_pad_mask);
}

// Round 5
// 87.955 us; speedup vs baseline: 4.5117x; 1.1509x over previous
//
#include <hip/hip_runtime.h>
#include <hip/hip_bf16.h>
#include <float.h>

typedef unsigned short u16;
typedef __attribute__((ext_vector_type(8))) short short8;  // 8 bf16 in 4 VGPRs
typedef __attribute__((ext_vector_type(4))) float f32x4;

#define NB       4
#define LQ       4096
#define LKV      512
#define DMODEL   512
#define NH       8
#define DH       64
#define KW       9
#define SCALE    0.125f

#define BM 64
#define BN 128
#define BK 32

__device__ inline float bf2f(u16 v) { return __uint_as_float(((unsigned)v) << 16); }
__device__ inline u16 f2bf(float f) {
    unsigned u = __float_as_uint(f);
    return (u16)((u + 0x7fffu + ((u >> 16) & 1u)) >> 16);   // RNE
}
__device__ inline void gload16(const u16* g, u16* l) {
    __builtin_amdgcn_global_load_lds((const __attribute__((address_space(1))) void*)g,
                                     (__attribute__((address_space(3))) void*)l, 16, 0, 0);
}
// convert 8 fp32 (2 float4) -> short8 bf16
__device__ inline short8 cvt8(const float4 v0, const float4 v1) {
    short8 s;
    s[0] = (short)f2bf(v0.x); s[1] = (short)f2bf(v0.y);
    s[2] = (short)f2bf(v0.z); s[3] = (short)f2bf(v0.w);
    s[4] = (short)f2bf(v1.x); s[5] = (short)f2bf(v1.y);
    s[6] = (short)f2bf(v1.z); s[7] = (short)f2bf(v1.w);
    return s;
}

// ---------------------------------------------------------------------------
// all 4 weight transposes in one launch (blockIdx.z selects matrix)
// ---------------------------------------------------------------------------
__global__ __launch_bounds__(256) void transpose4_kernel(
    const float* __restrict__ Wq, const float* __restrict__ Wk,
    const float* __restrict__ Wv, const float* __restrict__ Wo,
    u16* __restrict__ Wqt, u16* __restrict__ Wkvt, u16* __restrict__ Wot)
{
    __shared__ float tile[32][33];
    const int z = blockIdx.z;
    const float* src = (z == 0) ? Wq : (z == 1) ? Wk : (z == 2) ? Wv : Wo;
    u16* dst = (z == 0) ? Wqt : (z == 3) ? Wot : Wkvt;
    const int roff = (z == 2) ? DMODEL : 0;

    const int tx = threadIdx.x & 31, ty = threadIdx.x >> 5;   // 32x8
    const int x0 = blockIdx.x * 32, y0 = blockIdx.y * 32;
    #pragma unroll
    for (int i = 0; i < 4; ++i)
        tile[ty + i * 8][tx] = src[(y0 + ty + i * 8) * DMODEL + x0 + tx];
    __syncthreads();
    #pragma unroll
    for (int i = 0; i < 4; ++i)
        dst[(long long)(roff + x0 + ty + i * 8) * DMODEL + y0 + tx] = f2bf(tile[tx][ty + i * 8]);
}

// ---------------------------------------------------------------------------
// bf16 MFMA GEMM, 64x128 tile, BK=32, 4 waves (each 32x64, acc[2][4]).
// C[M,N] = A[M,K] @ Bt[N,K]^T + split bias.
// A_F32: A is fp32, reg-staged + converted to bf16 into LDS.
// OUT_F32: fp32 out + row mask; else bf16 out.
// ---------------------------------------------------------------------------
template<int A_F32, int OUT_F32>
__global__ __launch_bounds__(256, 4) void gemm64_kernel(
    const void* __restrict__ Ain, const u16* __restrict__ Bt,
    const float* __restrict__ bias0, const float* __restrict__ bias1, int nsplit,
    void* __restrict__ Cout, int M, int N, int K,
    const unsigned char* __restrict__ row_mask)
{
    __shared__ u16 As[BM * BK];   // 4 KB
    __shared__ u16 Bs[BN * BK];   // 8 KB

    const int tid = threadIdx.x;
    const int w = tid >> 6, l = tid & 63;
    const int wr = w >> 1, wc = w & 1;
    const int brow = blockIdx.y * BM, bcol = blockIdx.x * BN;

    const int rsub = l >> 2;
    const int csrc = (l & 3) ^ (rsub & 3);
    const u16*   gA  = (const u16*)Ain   + (long long)(brow + w * 16 + rsub) * K + csrc * 8;
    const float* gAf = (const float*)Ain + (long long)(brow + w * 16 + rsub) * K + csrc * 8;
    const u16* gB0 = Bt + (long long)(bcol + w * 32 + rsub) * K + csrc * 8;
    const u16* gB1 = gB0 + (long long)16 * K;
    u16* lA  = As + (w * 16) * BK;
    u16* lB0 = Bs + (w * 32) * BK;
    u16* lB1 = Bs + (w * 32 + 16) * BK;

    const int hi = l >> 4, lr = l & 15;
    const int cs = ((hi ^ (lr & 3)) * 8);

    f32x4 acc[2][4] = {};

    for (int k0 = 0; k0 < K; k0 += BK) {
        if (A_F32) {
            const float4 v0 = *(const float4*)(gAf + k0);
            const float4 v1 = *(const float4*)(gAf + k0 + 4);
            *(short8*)(lA + l * 8) = cvt8(v0, v1);
        } else {
            gload16(gA + k0, lA);
        }
        gload16(gB0 + k0, lB0);
        gload16(gB1 + k0, lB1);
        __syncthreads();

        short8 a[2], b[4];
        #pragma unroll
        for (int m = 0; m < 2; ++m)
            a[m] = *(const short8*)&As[(wr * 32 + m * 16 + lr) * BK + cs];
        #pragma unroll
        for (int n = 0; n < 4; ++n)
            b[n] = *(const short8*)&Bs[(wc * 64 + n * 16 + lr) * BK + cs];
        #pragma unroll
        for (int m = 0; m < 2; ++m)
            #pragma unroll
            for (int n = 0; n < 4; ++n)
                acc[m][n] = __builtin_amdgcn_mfma_f32_16x16x32_bf16(a[m], b[n], acc[m][n], 0, 0, 0);
        __syncthreads();
    }

    #pragma unroll
    for (int m = 0; m < 2; ++m) {
        #pragma unroll
        for (int n = 0; n < 4; ++n) {
            const int col = bcol + wc * 64 + n * 16 + lr;
            const float bv = (col < nsplit) ? bias0[col] : bias1[col - nsplit];
            #pragma unroll
            for (int r = 0; r < 4; ++r) {
                const int row = brow + wr * 32 + m * 16 + hi * 4 + r;
                const float v = acc[m][n][r] + bv;
                if (OUT_F32) {
                    ((float*)Cout)[(long long)row * N + col] =
                        (row_mask != nullptr && row_mask[row]) ? 0.0f : v;
                } else {
                    ((u16*)Cout)[(long long)row * N + col] = f2bf(v);
                }
            }
        }
    }
}

// ---------------------------------------------------------------------------
// FUSED Q-projection (64 rows x 2 heads) + windowed attention.
// GEMM: A = q fp32 (reg-staged->bf16), B = Wqt. Epilogue: acc+bias -> bf16
// swizzled LDS qt. Attention: 8 lanes per (row,head) item (dchunk=tid&7),
// 4 passes of 32 items; K/V reads are 128B-contiguous per item per j.
// ---------------------------------------------------------------------------
__global__ __launch_bounds__(256, 4) void qproj_attn_kernel(
    const float* __restrict__ Aq, const u16* __restrict__ Bt,
    const float* __restrict__ bias, const u16* __restrict__ khv,
    const int* __restrict__ seg_id, const unsigned char* __restrict__ kv_mask,
    u16* __restrict__ atb)
{
    __shared__ u16 As[BM * BK];     // 4 KB
    __shared__ u16 Bs[BN * BK];     // 8 KB
    __shared__ u16 qt[BM * BN];     // 16 KB, XOR-swizzled 16B chunks

    const int tid = threadIdx.x;
    const int w = tid >> 6, l = tid & 63;
    const int wr = w >> 1, wc = w & 1;
    const int brow = blockIdx.y * BM, bcol = blockIdx.x * BN;
    const int K = DMODEL;

    const int rsub = l >> 2;
    const int csrc = (l & 3) ^ (rsub & 3);
    const float* gAf = Aq + (long long)(brow + w * 16 + rsub) * K + csrc * 8;
    const u16* gB0 = Bt + (long long)(bcol + w * 32 + rsub) * K + csrc * 8;
    const u16* gB1 = gB0 + (long long)16 * K;
    u16* lA  = As + (w * 16) * BK;
    u16* lB0 = Bs + (w * 32) * BK;
    u16* lB1 = Bs + (w * 32 + 16) * BK;

    const int hi = l >> 4, lr = l & 15;
    const int cs = ((hi ^ (lr & 3)) * 8);

    f32x4 acc[2][4] = {};

    for (int k0 = 0; k0 < K; k0 += BK) {
        const float4 v0 = *(const float4*)(gAf + k0);
        const float4 v1 = *(const float4*)(gAf + k0 + 4);
        *(short8*)(lA + l * 8) = cvt8(v0, v1);
        gload16(gB0 + k0, lB0);
        gload16(gB1 + k0, lB1);
        __syncthreads();

        short8 a[2], b[4];
        #pragma unroll
        for (int m = 0; m < 2; ++m)
            a[m] = *(const short8*)&As[(wr * 32 + m * 16 + lr) * BK + cs];
        #pragma unroll
        for (int n = 0; n < 4; ++n)
            b[n] = *(const short8*)&Bs[(wc * 64 + n * 16 + lr) * BK + cs];
        #pragma unroll
        for (int m = 0; m < 2; ++m)
            #pragma unroll
            for (int n = 0; n < 4; ++n)
                acc[m][n] = __builtin_amdgcn_mfma_f32_16x16x32_bf16(a[m], b[n], acc[m][n], 0, 0, 0);
        __syncthreads();
    }

    // stash qh tile (+bias, bf16) into swizzled LDS
    #pragma unroll
    for (int m = 0; m < 2; ++m) {
        #pragma unroll
        for (int n = 0; n < 4; ++n) {
            const int col = wc * 64 + n * 16 + lr;
            const float bv = bias[bcol + col];
            const int g = col >> 3;
            #pragma unroll
            for (int r = 0; r < 4; ++r) {
                const int row = wr * 32 + m * 16 + hi * 4 + r;
                qt[row * BN + ((g ^ (row & 7)) << 3) + (col & 7)] =
                    f2bf(acc[m][n][r] + bv);
            }
        }
    }
    __syncthreads();

    // ---- attention: 8 lanes per item, 4 passes of 32 items ----
    const int dchunk = tid & 7;
    #pragma unroll
    for (int p = 0; p < 4; ++p) {
        const int it = p * 32 + (tid >> 3);       // 0..127
        const int row = it >> 1;                  // local row 0..63
        const int h2  = it & 1;
        const long long bl = brow + row;
        const int b = (int)(bl >> 12);            // LQ = 2^12
        const int head = (bcol >> 6) + h2;
        const int seg = seg_id[bl];
        const unsigned char* km = kv_mask + b * LKV;
        const u16* kvb = khv + (long long)b * LKV * 1024;

        // q: 8 dims from swizzled qt
        const int g = h2 * 8 + dchunk;
        const short8 q8 = *(const short8*)&qt[row * BN + ((g ^ (row & 7)) << 3)];
        float qf[8];
        #pragma unroll
        for (int e = 0; e < 8; ++e) qf[e] = bf2f((u16)q8[e]);

        int idxs[KW];
        float sc[KW];
        #pragma unroll
        for (int j = 0; j < KW; ++j) {
            int idx = seg - j;
            idx = idx < 0 ? 0 : (idx > LKV - 1 ? LKV - 1 : idx);
            idxs[j] = idx;
            const short8 k8 = *(const short8*)&kvb[(long long)idx * 1024 + head * DH + dchunk * 8];
            float d = 0.0f;
            #pragma unroll
            for (int e = 0; e < 8; ++e)
                d = fmaf(qf[e], bf2f((u16)k8[e]), d);
            d += __shfl_xor(d, 1);
            d += __shfl_xor(d, 2);
            d += __shfl_xor(d, 4);                // sum across the item's 8 lanes
            float s = d * SCALE;
            if (km[idx]) s = -FLT_MAX;
            sc[j] = s;
        }

        float mx = sc[0];
        #pragma unroll
        for (int j = 1; j < KW; ++j) mx = fmaxf(mx, sc[j]);
        float den = 0.0f;
        #pragma unroll
        for (int j = 0; j < KW; ++j) { sc[j] = __expf(sc[j] - mx); den += sc[j]; }
        const float inv = 1.0f / den;

        float o[8];
        #pragma unroll
        for (int e = 0; e < 8; ++e) o[e] = 0.0f;
        #pragma unroll
        for (int j = 0; j < KW; ++j) {
            const short8 v8 = *(const short8*)&kvb[(long long)idxs[j] * 1024 + DMODEL + head * DH + dchunk * 8];
            const float pj = sc[j];
            #pragma unroll
            for (int e = 0; e < 8; ++e)
                o[e] = fmaf(pj, bf2f((u16)v8[e]), o[e]);
        }

        short8 ov;
        #pragma unroll
        for (int e = 0; e < 8; ++e) ov[e] = (short)f2bf(o[e] * inv);
        *(short8*)&atb[bl * DMODEL + head * DH + dchunk * 8] = ov;
    }
}

extern "C" void kernel_launch(void* const* d_in, const int* in_sizes, int n_in,
                              void* d_out, int out_size, void* d_ws, size_t ws_size,
                              hipStream_t stream) {
    const float*         q          = (const float*)d_in[0];
    const float*         kv_src     = (const float*)d_in[1];
    const int*           seg_id     = (const int*)d_in[2];
    const unsigned char* kv_mask    = (const unsigned char*)d_in[3];
    const unsigned char* q_pad_mask = (const unsigned char*)d_in[4];
    const float*         Wq         = (const float*)d_in[5];
    const float*         bq         = (const float*)d_in[6];
    const float*         Wk         = (const float*)d_in[7];
    const float*         bk         = (const float*)d_in[8];
    const float*         Wv         = (const float*)d_in[9];
    const float*         bv         = (const float*)d_in[10];
    const float*         Wo         = (const float*)d_in[11];
    const float*         bo         = (const float*)d_in[12];
    float* out = (float*)d_out;

    const long long MQ  = (long long)NB * LQ;    // 16384
    const long long MKV = (long long)NB * LKV;   // 2048

    char* wsb = (char*)d_ws;
    u16* Wqt  = (u16*)wsb;  wsb += DMODEL * DMODEL * 2;       // 0.5 MB
    u16* Wkvt = (u16*)wsb;  wsb += 2 * DMODEL * DMODEL * 2;   //  1 MB
    u16* Wot  = (u16*)wsb;  wsb += DMODEL * DMODEL * 2;       // 0.5 MB
    u16* khv  = (u16*)wsb;  wsb += MKV * 2 * DMODEL * 2;      //  4 MB
    u16* atb  = (u16*)wsb;  wsb += MQ  * DMODEL * 2;          // 16 MB

    dim3 blk(256);

    transpose4_kernel<<<dim3(DMODEL / 32, DMODEL / 32, 4), blk, 0, stream>>>(
        Wq, Wk, Wv, Wo, Wqt, Wkvt, Wot);

    // fused K+V projection from fp32 source: C[MKV][1024] (K | V)
    gemm64_kernel<1, 0><<<dim3(2 * DMODEL / BN, MKV / BM), blk, 0, stream>>>(
        kv_src, Wkvt, bk, bv, DMODEL, khv, (int)MKV, 2 * DMODEL, DMODEL, nullptr);

    // fused Q projection (fp32 source) + windowed attention -> atb
    qproj_attn_kernel<<<dim3(DMODEL / BN, MQ / BM), blk, 0, stream>>>(
        q, Wqt, bq, khv, seg_id, kv_mask, atb);

    // output projection + pad-mask zeroing (fp32 out)
    gemm64_kernel<0, 1><<<dim3(DMODEL / BN, MQ / BM), blk, 0, stream>>>(
        atb, Wot, bo, bo, DMODEL, out, (int)MQ, DMODEL, DMODEL, q_pad_mask);
}

// Round 6
// 83.089 us; speedup vs baseline: 4.7760x; 1.0586x over previous
//
#include <hip/hip_runtime.h>
#include <hip/hip_bf16.h>
#include <float.h>

typedef unsigned short u16;
typedef __attribute__((ext_vector_type(8))) short short8;  // 8 bf16 in 4 VGPRs
typedef __attribute__((ext_vector_type(4))) float f32x4;

#define NB       4
#define LQ       4096
#define LKV      512
#define DMODEL   512
#define NH       8
#define DH       64
#define KW       9
#define SCALE    0.125f

#define BM 64
#define BN 128
#define BK 32

__device__ inline float bf2f(u16 v) { return __uint_as_float(((unsigned)v) << 16); }
__device__ inline u16 f2bf(float f) {
    unsigned u = __float_as_uint(f);
    return (u16)((u + 0x7fffu + ((u >> 16) & 1u)) >> 16);   // RNE
}
__device__ inline void gload16(const u16* g, u16* l) {
    __builtin_amdgcn_global_load_lds((const __attribute__((address_space(1))) void*)g,
                                     (__attribute__((address_space(3))) void*)l, 16, 0, 0);
}
__device__ inline short8 cvt8(const float4 v0, const float4 v1) {
    short8 s;
    s[0] = (short)f2bf(v0.x); s[1] = (short)f2bf(v0.y);
    s[2] = (short)f2bf(v0.z); s[3] = (short)f2bf(v0.w);
    s[4] = (short)f2bf(v1.x); s[5] = (short)f2bf(v1.y);
    s[6] = (short)f2bf(v1.z); s[7] = (short)f2bf(v1.w);
    return s;
}
// XCD-chunked bijective swizzle (nwg % 8 == 0): consecutive work ids stay on one XCD
__device__ inline int xcd_swz(int id, int nwg) {
    const int cpx = nwg >> 3;
    return (id & 7) * cpx + (id >> 3);
}

// ---------------------------------------------------------------------------
// all 4 weight transposes in one launch (blockIdx.z selects matrix)
// ---------------------------------------------------------------------------
__global__ __launch_bounds__(256) void transpose4_kernel(
    const float* __restrict__ Wq, const float* __restrict__ Wk,
    const float* __restrict__ Wv, const float* __restrict__ Wo,
    u16* __restrict__ Wqt, u16* __restrict__ Wkvt, u16* __restrict__ Wot)
{
    __shared__ float tile[32][33];
    const int z = blockIdx.z;
    const float* src = (z == 0) ? Wq : (z == 1) ? Wk : (z == 2) ? Wv : Wo;
    u16* dst = (z == 0) ? Wqt : (z == 3) ? Wot : Wkvt;
    const int roff = (z == 2) ? DMODEL : 0;

    const int tx = threadIdx.x & 31, ty = threadIdx.x >> 5;   // 32x8
    const int x0 = blockIdx.x * 32, y0 = blockIdx.y * 32;
    #pragma unroll
    for (int i = 0; i < 4; ++i)
        tile[ty + i * 8][tx] = src[(y0 + ty + i * 8) * DMODEL + x0 + tx];
    __syncthreads();
    #pragma unroll
    for (int i = 0; i < 4; ++i)
        dst[(long long)(roff + x0 + ty + i * 8) * DMODEL + y0 + tx] = f2bf(tile[tx][ty + i * 8]);
}

// ---------------------------------------------------------------------------
// bf16 MFMA GEMM, 64x128 tile, BK=32, 4 waves (each 32x64, acc[2][4]).
// 1D grid with XCD-chunked swizzle; cshift = log2(N/BN).
// A_F32: fp32 A reg-staged (+prefetch under MFMA) -> bf16 LDS.
// OUT_F32: fp32 out + row mask; else bf16 out.
// ---------------------------------------------------------------------------
template<int A_F32, int OUT_F32>
__global__ __launch_bounds__(256, 6) void gemm64_kernel(
    const void* __restrict__ Ain, const u16* __restrict__ Bt,
    const float* __restrict__ bias0, const float* __restrict__ bias1, int nsplit,
    void* __restrict__ Cout, int M, int N, int K, int cshift,
    const unsigned char* __restrict__ row_mask)
{
    __shared__ u16 As[BM * BK];   // 4 KB
    __shared__ u16 Bs[BN * BK];   // 8 KB

    const int tid = threadIdx.x;
    const int w = tid >> 6, l = tid & 63;
    const int wr = w >> 1, wc = w & 1;

    const int wg = xcd_swz((int)blockIdx.x, (int)gridDim.x);
    const int bx = wg & ((1 << cshift) - 1);
    const int by = wg >> cshift;
    const int brow = by * BM, bcol = bx * BN;

    const int rsub = l >> 2;
    const int csrc = (l & 3) ^ (rsub & 3);
    const u16*   gA  = (const u16*)Ain   + (long long)(brow + w * 16 + rsub) * K + csrc * 8;
    const float* gAf = (const float*)Ain + (long long)(brow + w * 16 + rsub) * K + csrc * 8;
    const u16* gB0 = Bt + (long long)(bcol + w * 32 + rsub) * K + csrc * 8;
    const u16* gB1 = gB0 + (long long)16 * K;
    u16* lA  = As + (w * 16) * BK;
    u16* lB0 = Bs + (w * 32) * BK;
    u16* lB1 = Bs + (w * 32 + 16) * BK;

    const int hi = l >> 4, lr = l & 15;
    const int cs = ((hi ^ (lr & 3)) * 8);

    f32x4 acc[2][4] = {};

    float4 v0, v1;
    if (A_F32) { v0 = *(const float4*)(gAf); v1 = *(const float4*)(gAf + 4); }

    for (int k0 = 0; k0 < K; k0 += BK) {
        if (A_F32) {
            *(short8*)(lA + l * 8) = cvt8(v0, v1);
        } else {
            gload16(gA + k0, lA);
        }
        gload16(gB0 + k0, lB0);
        gload16(gB1 + k0, lB1);
        __syncthreads();

        if (A_F32 && k0 + BK < K) {               // prefetch under MFMA phase
            v0 = *(const float4*)(gAf + k0 + BK);
            v1 = *(const float4*)(gAf + k0 + BK + 4);
        }

        short8 a[2], b[4];
        #pragma unroll
        for (int m = 0; m < 2; ++m)
            a[m] = *(const short8*)&As[(wr * 32 + m * 16 + lr) * BK + cs];
        #pragma unroll
        for (int n = 0; n < 4; ++n)
            b[n] = *(const short8*)&Bs[(wc * 64 + n * 16 + lr) * BK + cs];
        #pragma unroll
        for (int m = 0; m < 2; ++m)
            #pragma unroll
            for (int n = 0; n < 4; ++n)
                acc[m][n] = __builtin_amdgcn_mfma_f32_16x16x32_bf16(a[m], b[n], acc[m][n], 0, 0, 0);
        __syncthreads();
    }

    #pragma unroll
    for (int m = 0; m < 2; ++m) {
        #pragma unroll
        for (int n = 0; n < 4; ++n) {
            const int col = bcol + wc * 64 + n * 16 + lr;
            const float bv = (col < nsplit) ? bias0[col] : bias1[col - nsplit];
            #pragma unroll
            for (int r = 0; r < 4; ++r) {
                const int row = brow + wr * 32 + m * 16 + hi * 4 + r;
                const float v = acc[m][n][r] + bv;
                if (OUT_F32) {
                    ((float*)Cout)[(long long)row * N + col] =
                        (row_mask != nullptr && row_mask[row]) ? 0.0f : v;
                } else {
                    ((u16*)Cout)[(long long)row * N + col] = f2bf(v);
                }
            }
        }
    }
}

// ---------------------------------------------------------------------------
// FUSED Q-projection (64 rows x 2 heads) + windowed attention.
// LDS aliased: k-loop uses smem[0..6144) as As|Bs; tail reuses all 8192 as qt.
// Attention: 8 lanes per (row,head) item, 4 passes of 32 items.
// ---------------------------------------------------------------------------
__global__ __launch_bounds__(256, 6) void qproj_attn_kernel(
    const float* __restrict__ Aq, const u16* __restrict__ Bt,
    const float* __restrict__ bias, const u16* __restrict__ khv,
    const int* __restrict__ seg_id, const unsigned char* __restrict__ kv_mask,
    u16* __restrict__ atb)
{
    __shared__ u16 smem[BM * BN];   // 16 KB total
    u16* As = smem;                 // 2048 elems (k-loop)
    u16* Bs = smem + BM * BK;       // 4096 elems (k-loop)
    u16* qt = smem;                 // 8192 elems (tail, after final barrier)

    const int tid = threadIdx.x;
    const int w = tid >> 6, l = tid & 63;
    const int wr = w >> 1, wc = w & 1;

    const int wg = xcd_swz((int)blockIdx.x, (int)gridDim.x);
    const int bx = wg & 3;                    // 4 col blocks
    const int by = wg >> 2;
    const int brow = by * BM, bcol = bx * BN;
    const int K = DMODEL;

    const int rsub = l >> 2;
    const int csrc = (l & 3) ^ (rsub & 3);
    const float* gAf = Aq + (long long)(brow + w * 16 + rsub) * K + csrc * 8;
    const u16* gB0 = Bt + (long long)(bcol + w * 32 + rsub) * K + csrc * 8;
    const u16* gB1 = gB0 + (long long)16 * K;
    u16* lA  = As + (w * 16) * BK;
    u16* lB0 = Bs + (w * 32) * BK;
    u16* lB1 = Bs + (w * 32 + 16) * BK;

    const int hi = l >> 4, lr = l & 15;
    const int cs = ((hi ^ (lr & 3)) * 8);

    f32x4 acc[2][4] = {};

    float4 v0 = *(const float4*)(gAf);
    float4 v1 = *(const float4*)(gAf + 4);

    for (int k0 = 0; k0 < K; k0 += BK) {
        *(short8*)(lA + l * 8) = cvt8(v0, v1);
        gload16(gB0 + k0, lB0);
        gload16(gB1 + k0, lB1);
        __syncthreads();

        if (k0 + BK < K) {
            v0 = *(const float4*)(gAf + k0 + BK);
            v1 = *(const float4*)(gAf + k0 + BK + 4);
        }

        short8 a[2], b[4];
        #pragma unroll
        for (int m = 0; m < 2; ++m)
            a[m] = *(const short8*)&As[(wr * 32 + m * 16 + lr) * BK + cs];
        #pragma unroll
        for (int n = 0; n < 4; ++n)
            b[n] = *(const short8*)&Bs[(wc * 64 + n * 16 + lr) * BK + cs];
        #pragma unroll
        for (int m = 0; m < 2; ++m)
            #pragma unroll
            for (int n = 0; n < 4; ++n)
                acc[m][n] = __builtin_amdgcn_mfma_f32_16x16x32_bf16(a[m], b[n], acc[m][n], 0, 0, 0);
        __syncthreads();                        // also: last read of As/Bs done
    }

    // stash qh tile (+bias, bf16) into swizzled LDS (aliases As/Bs — safe after barrier)
    #pragma unroll
    for (int m = 0; m < 2; ++m) {
        #pragma unroll
        for (int n = 0; n < 4; ++n) {
            const int col = wc * 64 + n * 16 + lr;
            const float bv = bias[bcol + col];
            const int g = col >> 3;
            #pragma unroll
            for (int r = 0; r < 4; ++r) {
                const int row = wr * 32 + m * 16 + hi * 4 + r;
                qt[row * BN + ((g ^ (row & 7)) << 3) + (col & 7)] =
                    f2bf(acc[m][n][r] + bv);
            }
        }
    }
    __syncthreads();

    // ---- attention: 8 lanes per item, 4 passes of 32 items ----
    const int dchunk = tid & 7;
    #pragma unroll
    for (int p = 0; p < 4; ++p) {
        const int it = p * 32 + (tid >> 3);       // 0..127
        const int row = it >> 1;                  // local row 0..63
        const int h2  = it & 1;
        const long long bl = brow + row;
        const int b = (int)(bl >> 12);            // LQ = 2^12
        const int head = (bcol >> 6) + h2;
        const int seg = seg_id[bl];
        const unsigned char* km = kv_mask + b * LKV;
        const u16* kvb = khv + (long long)b * LKV * 1024;

        const int g = h2 * 8 + dchunk;
        const short8 q8 = *(const short8*)&qt[row * BN + ((g ^ (row & 7)) << 3)];
        float qf[8];
        #pragma unroll
        for (int e = 0; e < 8; ++e) qf[e] = bf2f((u16)q8[e]);

        int idxs[KW];
        float sc[KW];
        #pragma unroll
        for (int j = 0; j < KW; ++j) {
            int idx = seg - j;
            idx = idx < 0 ? 0 : (idx > LKV - 1 ? LKV - 1 : idx);
            idxs[j] = idx;
            const short8 k8 = *(const short8*)&kvb[(long long)idx * 1024 + head * DH + dchunk * 8];
            float d = 0.0f;
            #pragma unroll
            for (int e = 0; e < 8; ++e)
                d = fmaf(qf[e], bf2f((u16)k8[e]), d);
            d += __shfl_xor(d, 1);
            d += __shfl_xor(d, 2);
            d += __shfl_xor(d, 4);
            float s = d * SCALE;
            if (km[idx]) s = -FLT_MAX;
            sc[j] = s;
        }

        float mx = sc[0];
        #pragma unroll
        for (int j = 1; j < KW; ++j) mx = fmaxf(mx, sc[j]);
        float den = 0.0f;
        #pragma unroll
        for (int j = 0; j < KW; ++j) { sc[j] = __expf(sc[j] - mx); den += sc[j]; }
        const float inv = 1.0f / den;

        float o[8];
        #pragma unroll
        for (int e = 0; e < 8; ++e) o[e] = 0.0f;
        #pragma unroll
        for (int j = 0; j < KW; ++j) {
            const short8 v8 = *(const short8*)&kvb[(long long)idxs[j] * 1024 + DMODEL + head * DH + dchunk * 8];
            const float pj = sc[j];
            #pragma unroll
            for (int e = 0; e < 8; ++e)
                o[e] = fmaf(pj, bf2f((u16)v8[e]), o[e]);
        }

        short8 ov;
        #pragma unroll
        for (int e = 0; e < 8; ++e) ov[e] = (short)f2bf(o[e] * inv);
        *(short8*)&atb[bl * DMODEL + head * DH + dchunk * 8] = ov;
    }
}

extern "C" void kernel_launch(void* const* d_in, const int* in_sizes, int n_in,
                              void* d_out, int out_size, void* d_ws, size_t ws_size,
                              hipStream_t stream) {
    const float*         q          = (const float*)d_in[0];
    const float*         kv_src     = (const float*)d_in[1];
    const int*           seg_id     = (const int*)d_in[2];
    const unsigned char* kv_mask    = (const unsigned char*)d_in[3];
    const unsigned char* q_pad_mask = (const unsigned char*)d_in[4];
    const float*         Wq         = (const float*)d_in[5];
    const float*         bq         = (const float*)d_in[6];
    const float*         Wk         = (const float*)d_in[7];
    const float*         bk         = (const float*)d_in[8];
    const float*         Wv         = (const float*)d_in[9];
    const float*         bv         = (const float*)d_in[10];
    const float*         Wo         = (const float*)d_in[11];
    const float*         bo         = (const float*)d_in[12];
    float* out = (float*)d_out;

    const long long MQ  = (long long)NB * LQ;    // 16384
    const long long MKV = (long long)NB * LKV;   // 2048

    char* wsb = (char*)d_ws;
    u16* Wqt  = (u16*)wsb;  wsb += DMODEL * DMODEL * 2;       // 0.5 MB
    u16* Wkvt = (u16*)wsb;  wsb += 2 * DMODEL * DMODEL * 2;   //  1 MB
    u16* Wot  = (u16*)wsb;  wsb += DMODEL * DMODEL * 2;       // 0.5 MB
    u16* khv  = (u16*)wsb;  wsb += MKV * 2 * DMODEL * 2;      //  4 MB
    u16* atb  = (u16*)wsb;  wsb += MQ  * DMODEL * 2;          // 16 MB

    dim3 blk(256);

    transpose4_kernel<<<dim3(DMODEL / 32, DMODEL / 32, 4), blk, 0, stream>>>(
        Wq, Wk, Wv, Wo, Wqt, Wkvt, Wot);

    // fused K+V projection from fp32 source: C[MKV][1024] (K | V); 256 blocks
    gemm64_kernel<1, 0><<<dim3((unsigned)((2 * DMODEL / BN) * (MKV / BM))), blk, 0, stream>>>(
        kv_src, Wkvt, bk, bv, DMODEL, khv, (int)MKV, 2 * DMODEL, DMODEL, 3, nullptr);

    // fused Q projection (fp32 source) + windowed attention -> atb; 1024 blocks
    qproj_attn_kernel<<<dim3((unsigned)((DMODEL / BN) * (MQ / BM))), blk, 0, stream>>>(
        q, Wqt, bq, khv, seg_id, kv_mask, atb);

    // output projection + pad-mask zeroing (fp32 out); 1024 blocks
    gemm64_kernel<0, 1><<<dim3((unsigned)((DMODEL / BN) * (MQ / BM))), blk, 0, stream>>>(
        atb, Wot, bo, bo, DMODEL, out, (int)MQ, DMODEL, DMODEL, 2, q_pad_mask);
}

// Round 7
// 72.983 us; speedup vs baseline: 5.4373x; 1.1385x over previous
//
#include <hip/hip_runtime.h>
#include <hip/hip_bf16.h>
#include <float.h>

typedef unsigned short u16;
typedef __attribute__((ext_vector_type(8))) short short8;  // 8 bf16 in 4 VGPRs
typedef __attribute__((ext_vector_type(4))) float f32x4;

#define NB       4
#define LQ       4096
#define LKV      512
#define DMODEL   512
#define NH       8
#define DH       64
#define KW       9
#define SCALE    0.125f

#define BM 64
#define BN 64
#define BK 64

__device__ inline float bf2f(u16 v) { return __uint_as_float(((unsigned)v) << 16); }
__device__ inline u16 f2bf(float f) {
    unsigned u = __float_as_uint(f);
    return (u16)((u + 0x7fffu + ((u >> 16) & 1u)) >> 16);   // RNE
}
__device__ inline void gload16(const u16* g, u16* l) {
    __builtin_amdgcn_global_load_lds((const __attribute__((address_space(1))) void*)g,
                                     (__attribute__((address_space(3))) void*)l, 16, 0, 0);
}
__device__ inline short8 cvt8(const float4 v0, const float4 v1) {
    short8 s;
    s[0] = (short)f2bf(v0.x); s[1] = (short)f2bf(v0.y);
    s[2] = (short)f2bf(v0.z); s[3] = (short)f2bf(v0.w);
    s[4] = (short)f2bf(v1.x); s[5] = (short)f2bf(v1.y);
    s[6] = (short)f2bf(v1.z); s[7] = (short)f2bf(v1.w);
    return s;
}
// XCD-chunked bijective swizzle (nwg % 8 == 0)
__device__ inline int xcd_swz(int id, int nwg) {
    const int cpx = nwg >> 3;
    return (id & 7) * cpx + (id >> 3);
}

// ---------------------------------------------------------------------------
// all 4 weight transposes in one launch
// ---------------------------------------------------------------------------
__global__ __launch_bounds__(256) void transpose4_kernel(
    const float* __restrict__ Wq, const float* __restrict__ Wk,
    const float* __restrict__ Wv, const float* __restrict__ Wo,
    u16* __restrict__ Wqt, u16* __restrict__ Wkvt, u16* __restrict__ Wot)
{
    __shared__ float tile[32][33];
    const int z = blockIdx.z;
    const float* src = (z == 0) ? Wq : (z == 1) ? Wk : (z == 2) ? Wv : Wo;
    u16* dst = (z == 0) ? Wqt : (z == 3) ? Wot : Wkvt;
    const int roff = (z == 2) ? DMODEL : 0;

    const int tx = threadIdx.x & 31, ty = threadIdx.x >> 5;   // 32x8
    const int x0 = blockIdx.x * 32, y0 = blockIdx.y * 32;
    #pragma unroll
    for (int i = 0; i < 4; ++i)
        tile[ty + i * 8][tx] = src[(y0 + ty + i * 8) * DMODEL + x0 + tx];
    __syncthreads();
    #pragma unroll
    for (int i = 0; i < 4; ++i)
        dst[(long long)(roff + x0 + ty + i * 8) * DMODEL + y0 + tx] = f2bf(tile[tx][ty + i * 8]);
}

// ---------------------------------------------------------------------------
// bf16 MFMA GEMM, 64x64 tile, BK=64, 4 waves (each 32x32, acc[2][2]).
// 8 blocks/CU -> 32 waves/CU. 1D grid, XCD-chunked swizzle, cshift=log2(N/BN).
// A_F32: fp32 A reg-staged (+prefetch) -> bf16 LDS. OUT_F32: fp32 out + mask.
// 8-chunk XOR swizzle: LDS[row][slot] holds source k-chunk (slot ^ (row&7)).
// ---------------------------------------------------------------------------
template<int A_F32, int OUT_F32>
__global__ __launch_bounds__(256, 8) void gemm64_kernel(
    const void* __restrict__ Ain, const u16* __restrict__ Bt,
    const float* __restrict__ bias0, const float* __restrict__ bias1, int nsplit,
    void* __restrict__ Cout, int N, int K, int cshift,
    const unsigned char* __restrict__ row_mask)
{
    __shared__ u16 As[BM * BK];   // 8 KB
    __shared__ u16 Bs[BN * BK];   // 8 KB

    const int tid = threadIdx.x;
    const int w = tid >> 6, l = tid & 63;
    const int wr = w >> 1, wc = w & 1;

    const int wg = xcd_swz((int)blockIdx.x, (int)gridDim.x);
    const int bx = wg & ((1 << cshift) - 1);
    const int by = wg >> cshift;
    const int brow = by * BM, bcol = bx * BN;

    // staging: wave w owns rows w*16..w*16+15 of A and B, as 2 x 8-row groups.
    const int srow   = l >> 3;                 // row within 8-row group
    const int schunk = ((l & 7) ^ srow) * 8;   // pre-swizzled source k-offset
    const long long ar0 = brow + w * 16 + srow;
    const long long br0 = bcol + w * 16 + srow;
    const u16*   gA0  = (const u16*)Ain   + ar0 * K + schunk;
    const u16*   gA1  = gA0 + 8 * K;
    const float* gAf0 = (const float*)Ain + ar0 * K + schunk;
    const float* gAf1 = gAf0 + 8 * K;
    const u16* gB0 = Bt + br0 * K + schunk;
    const u16* gB1 = gB0 + 8 * K;
    u16* lA0 = As + (w * 16) * BK;
    u16* lA1 = As + (w * 16 + 8) * BK;
    u16* lB0 = Bs + (w * 16) * BK;
    u16* lB1 = Bs + (w * 16 + 8) * BK;

    const int hi = l >> 4, lr = l & 15;
    const int r7 = lr & 7;

    f32x4 acc[2][2] = {};

    float4 p0, p1, p2, p3;
    if (A_F32) {
        p0 = *(const float4*)(gAf0);     p1 = *(const float4*)(gAf0 + 4);
        p2 = *(const float4*)(gAf1);     p3 = *(const float4*)(gAf1 + 4);
    }

    for (int k0 = 0; k0 < K; k0 += BK) {
        if (A_F32) {
            *(short8*)(lA0 + l * 8) = cvt8(p0, p1);
            *(short8*)(lA1 + l * 8) = cvt8(p2, p3);
        } else {
            gload16(gA0 + k0, lA0);
            gload16(gA1 + k0, lA1);
        }
        gload16(gB0 + k0, lB0);
        gload16(gB1 + k0, lB1);
        __syncthreads();

        if (A_F32 && k0 + BK < K) {       // prefetch next iter under MFMA
            p0 = *(const float4*)(gAf0 + k0 + BK); p1 = *(const float4*)(gAf0 + k0 + BK + 4);
            p2 = *(const float4*)(gAf1 + k0 + BK); p3 = *(const float4*)(gAf1 + k0 + BK + 4);
        }

        #pragma unroll
        for (int g2 = 0; g2 < 2; ++g2) {
            const int slot = ((g2 * 4 + hi) ^ r7) * 8;
            short8 a[2], b[2];
            #pragma unroll
            for (int m = 0; m < 2; ++m)
                a[m] = *(const short8*)&As[(wr * 32 + m * 16 + lr) * BK + slot];
            #pragma unroll
            for (int n = 0; n < 2; ++n)
                b[n] = *(const short8*)&Bs[(wc * 32 + n * 16 + lr) * BK + slot];
            #pragma unroll
            for (int m = 0; m < 2; ++m)
                #pragma unroll
                for (int n = 0; n < 2; ++n)
                    acc[m][n] = __builtin_amdgcn_mfma_f32_16x16x32_bf16(a[m], b[n], acc[m][n], 0, 0, 0);
        }
        __syncthreads();
    }

    #pragma unroll
    for (int m = 0; m < 2; ++m) {
        #pragma unroll
        for (int n = 0; n < 2; ++n) {
            const int col = bcol + wc * 32 + n * 16 + lr;
            const float bv = (col < nsplit) ? bias0[col] : bias1[col - nsplit];
            #pragma unroll
            for (int r = 0; r < 4; ++r) {
                const int row = brow + wr * 32 + m * 16 + hi * 4 + r;
                const float v = acc[m][n][r] + bv;
                if (OUT_F32) {
                    ((float*)Cout)[(long long)row * N + col] =
                        (row_mask != nullptr && row_mask[row]) ? 0.0f : v;
                } else {
                    ((u16*)Cout)[(long long)row * N + col] = f2bf(v);
                }
            }
        }
    }
}

// ---------------------------------------------------------------------------
// FUSED Q-projection (64 rows x 1 head) + windowed attention.
// Same 64x64 GEMM; qt[64][64] aliases As (dead after final barrier).
// Attention: 8 lanes per (row) item, 2 passes of 32 items; 128B-contiguous K/V.
// ---------------------------------------------------------------------------
__global__ __launch_bounds__(256, 8) void qproj_attn_kernel(
    const float* __restrict__ Aq, const u16* __restrict__ Bt,
    const float* __restrict__ bias, const u16* __restrict__ khv,
    const int* __restrict__ seg_id, const unsigned char* __restrict__ kv_mask,
    u16* __restrict__ atb)
{
    __shared__ u16 smem[BM * BK + BN * BK];   // 16 KB
    u16* As = smem;
    u16* Bs = smem + BM * BK;
    u16* qt = smem;                            // 8 KB, reused after k-loop

    const int tid = threadIdx.x;
    const int w = tid >> 6, l = tid & 63;
    const int wr = w >> 1, wc = w & 1;

    const int wg = xcd_swz((int)blockIdx.x, (int)gridDim.x);
    const int bx = wg & 7;                     // 8 col blocks = 8 heads
    const int by = wg >> 3;
    const int brow = by * BM, bcol = bx * BN;
    const int K = DMODEL;

    const int srow   = l >> 3;
    const int schunk = ((l & 7) ^ srow) * 8;
    const long long ar0 = brow + w * 16 + srow;
    const long long br0 = bcol + w * 16 + srow;
    const float* gAf0 = Aq + ar0 * K + schunk;
    const float* gAf1 = gAf0 + 8 * K;
    const u16* gB0 = Bt + br0 * K + schunk;
    const u16* gB1 = gB0 + 8 * K;
    u16* lA0 = As + (w * 16) * BK;
    u16* lA1 = As + (w * 16 + 8) * BK;
    u16* lB0 = Bs + (w * 16) * BK;
    u16* lB1 = Bs + (w * 16 + 8) * BK;

    const int hi = l >> 4, lr = l & 15;
    const int r7 = lr & 7;

    f32x4 acc[2][2] = {};

    float4 p0 = *(const float4*)(gAf0), p1 = *(const float4*)(gAf0 + 4);
    float4 p2 = *(const float4*)(gAf1), p3 = *(const float4*)(gAf1 + 4);

    for (int k0 = 0; k0 < K; k0 += BK) {
        *(short8*)(lA0 + l * 8) = cvt8(p0, p1);
        *(short8*)(lA1 + l * 8) = cvt8(p2, p3);
        gload16(gB0 + k0, lB0);
        gload16(gB1 + k0, lB1);
        __syncthreads();

        if (k0 + BK < K) {
            p0 = *(const float4*)(gAf0 + k0 + BK); p1 = *(const float4*)(gAf0 + k0 + BK + 4);
            p2 = *(const float4*)(gAf1 + k0 + BK); p3 = *(const float4*)(gAf1 + k0 + BK + 4);
        }

        #pragma unroll
        for (int g2 = 0; g2 < 2; ++g2) {
            const int slot = ((g2 * 4 + hi) ^ r7) * 8;
            short8 a[2], b[2];
            #pragma unroll
            for (int m = 0; m < 2; ++m)
                a[m] = *(const short8*)&As[(wr * 32 + m * 16 + lr) * BK + slot];
            #pragma unroll
            for (int n = 0; n < 2; ++n)
                b[n] = *(const short8*)&Bs[(wc * 32 + n * 16 + lr) * BK + slot];
            #pragma unroll
            for (int m = 0; m < 2; ++m)
                #pragma unroll
                for (int n = 0; n < 2; ++n)
                    acc[m][n] = __builtin_amdgcn_mfma_f32_16x16x32_bf16(a[m], b[n], acc[m][n], 0, 0, 0);
        }
        __syncthreads();                       // last As/Bs reads complete
    }

    // stash qh tile (+bias, bf16) into chunk-swizzled qt (aliases As)
    #pragma unroll
    for (int m = 0; m < 2; ++m) {
        #pragma unroll
        for (int n = 0; n < 2; ++n) {
            const int col = wc * 32 + n * 16 + lr;
            const float bv = bias[bcol + col];
            #pragma unroll
            for (int r = 0; r < 4; ++r) {
                const int row = wr * 32 + m * 16 + hi * 4 + r;
                qt[row * BN + (((col >> 3) ^ (row & 7)) << 3) + (col & 7)] =
                    f2bf(acc[m][n][r] + bv);
            }
        }
    }
    __syncthreads();

    // ---- attention: 8 lanes per item, 2 passes of 32 items ----
    const int dchunk = tid & 7;
    const int head = bx;
    #pragma unroll
    for (int p = 0; p < 2; ++p) {
        const int row = p * 32 + (tid >> 3);      // local row 0..63
        const long long bl = brow + row;
        const int b = (int)(bl >> 12);            // LQ = 2^12
        const int seg = seg_id[bl];
        const unsigned char* km = kv_mask + b * LKV;
        const u16* kvb = khv + (long long)b * LKV * 1024;

        const short8 q8 = *(const short8*)&qt[row * BN + ((dchunk ^ (row & 7)) << 3)];
        float qf[8];
        #pragma unroll
        for (int e = 0; e < 8; ++e) qf[e] = bf2f((u16)q8[e]);

        int idxs[KW];
        float sc[KW];
        #pragma unroll
        for (int j = 0; j < KW; ++j) {
            int idx = seg - j;
            idx = idx < 0 ? 0 : (idx > LKV - 1 ? LKV - 1 : idx);
            idxs[j] = idx;
            const short8 k8 = *(const short8*)&kvb[(long long)idx * 1024 + head * DH + dchunk * 8];
            float d = 0.0f;
            #pragma unroll
            for (int e = 0; e < 8; ++e)
                d = fmaf(qf[e], bf2f((u16)k8[e]), d);
            d += __shfl_xor(d, 1);
            d += __shfl_xor(d, 2);
            d += __shfl_xor(d, 4);
            float s = d * SCALE;
            if (km[idx]) s = -FLT_MAX;
            sc[j] = s;
        }

        float mx = sc[0];
        #pragma unroll
        for (int j = 1; j < KW; ++j) mx = fmaxf(mx, sc[j]);
        float den = 0.0f;
        #pragma unroll
        for (int j = 0; j < KW; ++j) { sc[j] = __expf(sc[j] - mx); den += sc[j]; }
        const float inv = 1.0f / den;

        float o[8];
        #pragma unroll
        for (int e = 0; e < 8; ++e) o[e] = 0.0f;
        #pragma unroll
        for (int j = 0; j < KW; ++j) {
            const short8 v8 = *(const short8*)&kvb[(long long)idxs[j] * 1024 + DMODEL + head * DH + dchunk * 8];
            const float pj = sc[j];
            #pragma unroll
            for (int e = 0; e < 8; ++e)
                o[e] = fmaf(pj, bf2f((u16)v8[e]), o[e]);
        }

        short8 ov;
        #pragma unroll
        for (int e = 0; e < 8; ++e) ov[e] = (short)f2bf(o[e] * inv);
        *(short8*)&atb[bl * DMODEL + head * DH + dchunk * 8] = ov;
    }
}

extern "C" void kernel_launch(void* const* d_in, const int* in_sizes, int n_in,
                              void* d_out, int out_size, void* d_ws, size_t ws_size,
                              hipStream_t stream) {
    const float*         q          = (const float*)d_in[0];
    const float*         kv_src     = (const float*)d_in[1];
    const int*           seg_id     = (const int*)d_in[2];
    const unsigned char* kv_mask    = (const unsigned char*)d_in[3];
    const unsigned char* q_pad_mask = (const unsigned char*)d_in[4];
    const float*         Wq         = (const float*)d_in[5];
    const float*         bq         = (const float*)d_in[6];
    const float*         Wk         = (const float*)d_in[7];
    const float*         bk         = (const float*)d_in[8];
    const float*         Wv         = (const float*)d_in[9];
    const float*         bv         = (const float*)d_in[10];
    const float*         Wo         = (const float*)d_in[11];
    const float*         bo         = (const float*)d_in[12];
    float* out = (float*)d_out;

    const long long MQ  = (long long)NB * LQ;    // 16384
    const long long MKV = (long long)NB * LKV;   // 2048

    char* wsb = (char*)d_ws;
    u16* Wqt  = (u16*)wsb;  wsb += DMODEL * DMODEL * 2;       // 0.5 MB
    u16* Wkvt = (u16*)wsb;  wsb += 2 * DMODEL * DMODEL * 2;   //  1 MB
    u16* Wot  = (u16*)wsb;  wsb += DMODEL * DMODEL * 2;       // 0.5 MB
    u16* khv  = (u16*)wsb;  wsb += MKV * 2 * DMODEL * 2;      //  4 MB
    u16* atb  = (u16*)wsb;  wsb += MQ  * DMODEL * 2;          // 16 MB

    dim3 blk(256);

    transpose4_kernel<<<dim3(DMODEL / 32, DMODEL / 32, 4), blk, 0, stream>>>(
        Wq, Wk, Wv, Wo, Wqt, Wkvt, Wot);

    // fused K+V projection (fp32 A): C[2048][1024] (K | V); 512 blocks, cshift=4
    gemm64_kernel<1, 0><<<dim3((unsigned)((2 * DMODEL / BN) * (MKV / BM))), blk, 0, stream>>>(
        kv_src, Wkvt, bk, bv, DMODEL, khv, 2 * DMODEL, DMODEL, 4, nullptr);

    // fused Q projection (fp32 A) + windowed attention -> atb; 2048 blocks
    qproj_attn_kernel<<<dim3((unsigned)((DMODEL / BN) * (MQ / BM))), blk, 0, stream>>>(
        q, Wqt, bq, khv, seg_id, kv_mask, atb);

    // output projection + pad-mask zeroing (fp32 out); 2048 blocks, cshift=3
    gemm64_kernel<0, 1><<<dim3((unsigned)((DMODEL / BN) * (MQ / BM))), blk, 0, stream>>>(
        atb, Wot, bo, bo, DMODEL, out, DMODEL, DMODEL, 3, q_pad_mask);
}

// Round 8
// 71.949 us; speedup vs baseline: 5.5155x; 1.0144x over previous
//
#include <hip/hip_runtime.h>
#include <hip/hip_bf16.h>
#include <float.h>

typedef unsigned short u16;
typedef unsigned long long u64;
typedef __attribute__((ext_vector_type(8))) short short8;  // 8 bf16 in 4 VGPRs
typedef __attribute__((ext_vector_type(4))) float f32x4;

#define NB       4
#define LQ       4096
#define LKV      512
#define DMODEL   512
#define NH       8
#define DH       64
#define KW       9
#define SCALE    0.125f

#define BM 64
#define BN 64
#define BK 64

__device__ inline float bf2f(u16 v) { return __uint_as_float(((unsigned)v) << 16); }
// hardware packed fp32->bf16 (RNE), 2 elems / instruction
__device__ inline unsigned pk2(float a, float b) {
    unsigned r;
    asm("v_cvt_pk_bf16_f32 %0, %1, %2" : "=v"(r) : "v"(a), "v"(b));
    return r;
}
__device__ inline u16 f2bf(float f) {               // scalar fallback (transpose kernel)
    unsigned u = __float_as_uint(f);
    return (u16)((u + 0x7fffu + ((u >> 16) & 1u)) >> 16);
}
__device__ inline void gload16(const u16* g, u16* l) {
    __builtin_amdgcn_global_load_lds((const __attribute__((address_space(1))) void*)g,
                                     (__attribute__((address_space(3))) void*)l, 16, 0, 0);
}
__device__ inline short8 cvt8(const float4 v0, const float4 v1) {
    union { unsigned u[4]; short8 s; } r;
    r.u[0] = pk2(v0.x, v0.y);
    r.u[1] = pk2(v0.z, v0.w);
    r.u[2] = pk2(v1.x, v1.y);
    r.u[3] = pk2(v1.z, v1.w);
    return r.s;
}
// XCD-chunked bijective swizzle (nwg % 8 == 0)
__device__ inline int xcd_swz(int id, int nwg) {
    const int cpx = nwg >> 3;
    return (id & 7) * cpx + (id >> 3);
}

// ---------------------------------------------------------------------------
// all 4 weight transposes in one launch
// ---------------------------------------------------------------------------
__global__ __launch_bounds__(256) void transpose4_kernel(
    const float* __restrict__ Wq, const float* __restrict__ Wk,
    const float* __restrict__ Wv, const float* __restrict__ Wo,
    u16* __restrict__ Wqt, u16* __restrict__ Wkvt, u16* __restrict__ Wot)
{
    __shared__ float tile[32][33];
    const int z = blockIdx.z;
    const float* src = (z == 0) ? Wq : (z == 1) ? Wk : (z == 2) ? Wv : Wo;
    u16* dst = (z == 0) ? Wqt : (z == 3) ? Wot : Wkvt;
    const int roff = (z == 2) ? DMODEL : 0;

    const int tx = threadIdx.x & 31, ty = threadIdx.x >> 5;   // 32x8
    const int x0 = blockIdx.x * 32, y0 = blockIdx.y * 32;
    #pragma unroll
    for (int i = 0; i < 4; ++i)
        tile[ty + i * 8][tx] = src[(y0 + ty + i * 8) * DMODEL + x0 + tx];
    __syncthreads();
    #pragma unroll
    for (int i = 0; i < 4; ++i)
        dst[(long long)(roff + x0 + ty + i * 8) * DMODEL + y0 + tx] = f2bf(tile[tx][ty + i * 8]);
}

// ---------------------------------------------------------------------------
// bf16 MFMA GEMM, 64x64 tile, BK=64, 4 waves (each 32x32, acc[2][2]).
// 1D grid, XCD-chunked swizzle, cshift=log2(N/BN).
// A_F32: fp32 A reg-staged (+prefetch) -> bf16 LDS. OUT_F32: fp32 out + mask.
// PACK_MASK: block 0 additionally packs kv_mask into a bitmask in mbits.
// ---------------------------------------------------------------------------
template<int A_F32, int OUT_F32, int PACK_MASK>
__global__ __launch_bounds__(256, 8) void gemm64_kernel(
    const void* __restrict__ Ain, const u16* __restrict__ Bt,
    const float* __restrict__ bias0, const float* __restrict__ bias1, int nsplit,
    void* __restrict__ Cout, int N, int K, int cshift,
    const unsigned char* __restrict__ row_mask,
    const unsigned char* __restrict__ kv_mask_in, u64* __restrict__ mbits_out)
{
    __shared__ u16 As[BM * BK];   // 8 KB
    __shared__ u16 Bs[BN * BK];   // 8 KB

    const int tid = threadIdx.x;
    const int w = tid >> 6, l = tid & 63;
    const int wr = w >> 1, wc = w & 1;

    if (PACK_MASK) {
        if (blockIdx.x == 0 && tid < 36) {
            if (tid < 32) {
                const int b = tid >> 3, wd = tid & 7;
                const unsigned char* p = kv_mask_in + b * LKV + wd * 64;
                u64 m = 0;
                for (int i = 0; i < 64; ++i) m |= ((u64)(p[i] != 0)) << i;
                mbits_out[b * 9 + wd] = m;
            } else {
                mbits_out[(tid - 32) * 9 + 8] = 0ULL;
            }
        }
    }

    const int wg = xcd_swz((int)blockIdx.x, (int)gridDim.x);
    const int bx = wg & ((1 << cshift) - 1);
    const int by = wg >> cshift;
    const int brow = by * BM, bcol = bx * BN;

    const int srow   = l >> 3;                 // row within 8-row group
    const int schunk = ((l & 7) ^ srow) * 8;   // pre-swizzled source k-offset
    const long long ar0 = brow + w * 16 + srow;
    const long long br0 = bcol + w * 16 + srow;
    const u16*   gA0  = (const u16*)Ain   + ar0 * K + schunk;
    const u16*   gA1  = gA0 + 8 * K;
    const float* gAf0 = (const float*)Ain + ar0 * K + schunk;
    const float* gAf1 = gAf0 + 8 * K;
    const u16* gB0 = Bt + br0 * K + schunk;
    const u16* gB1 = gB0 + 8 * K;
    u16* lA0 = As + (w * 16) * BK;
    u16* lA1 = As + (w * 16 + 8) * BK;
    u16* lB0 = Bs + (w * 16) * BK;
    u16* lB1 = Bs + (w * 16 + 8) * BK;

    const int hi = l >> 4, lr = l & 15;
    const int r7 = lr & 7;

    f32x4 acc[2][2] = {};

    float4 p0, p1, p2, p3;
    if (A_F32) {
        p0 = *(const float4*)(gAf0);     p1 = *(const float4*)(gAf0 + 4);
        p2 = *(const float4*)(gAf1);     p3 = *(const float4*)(gAf1 + 4);
    }

    for (int k0 = 0; k0 < K; k0 += BK) {
        if (A_F32) {
            *(short8*)(lA0 + l * 8) = cvt8(p0, p1);
            *(short8*)(lA1 + l * 8) = cvt8(p2, p3);
        } else {
            gload16(gA0 + k0, lA0);
            gload16(gA1 + k0, lA1);
        }
        gload16(gB0 + k0, lB0);
        gload16(gB1 + k0, lB1);
        __syncthreads();

        if (A_F32 && k0 + BK < K) {       // prefetch next iter under MFMA
            p0 = *(const float4*)(gAf0 + k0 + BK); p1 = *(const float4*)(gAf0 + k0 + BK + 4);
            p2 = *(const float4*)(gAf1 + k0 + BK); p3 = *(const float4*)(gAf1 + k0 + BK + 4);
        }

        #pragma unroll
        for (int g2 = 0; g2 < 2; ++g2) {
            const int slot = ((g2 * 4 + hi) ^ r7) * 8;
            short8 a[2], b[2];
            #pragma unroll
            for (int m = 0; m < 2; ++m)
                a[m] = *(const short8*)&As[(wr * 32 + m * 16 + lr) * BK + slot];
            #pragma unroll
            for (int n = 0; n < 2; ++n)
                b[n] = *(const short8*)&Bs[(wc * 32 + n * 16 + lr) * BK + slot];
            #pragma unroll
            for (int m = 0; m < 2; ++m)
                #pragma unroll
                for (int n = 0; n < 2; ++n)
                    acc[m][n] = __builtin_amdgcn_mfma_f32_16x16x32_bf16(a[m], b[n], acc[m][n], 0, 0, 0);
        }
        __syncthreads();
    }

    #pragma unroll
    for (int m = 0; m < 2; ++m) {
        #pragma unroll
        for (int n = 0; n < 2; ++n) {
            const int col = bcol + wc * 32 + n * 16 + lr;
            const float bv = (col < nsplit) ? bias0[col] : bias1[col - nsplit];
            const int row0 = brow + wr * 32 + m * 16 + hi * 4;
            if (OUT_F32) {
                #pragma unroll
                for (int r = 0; r < 4; ++r) {
                    const int row = row0 + r;
                    const float v = acc[m][n][r] + bv;
                    ((float*)Cout)[(long long)row * N + col] =
                        (row_mask != nullptr && row_mask[row]) ? 0.0f : v;
                }
            } else {
                const unsigned pa = pk2(acc[m][n][0] + bv, acc[m][n][1] + bv);
                const unsigned pb = pk2(acc[m][n][2] + bv, acc[m][n][3] + bv);
                u16* cp = (u16*)Cout + (long long)row0 * N + col;
                cp[0]           = (u16)pa;
                cp[(long long)N]     = (u16)(pa >> 16);
                cp[(long long)2 * N] = (u16)pb;
                cp[(long long)3 * N] = (u16)(pb >> 16);
            }
        }
    }
}

// ---------------------------------------------------------------------------
// FUSED Q-projection (64 rows x 1 head) + windowed attention.
// qt[64][64] aliases As (dead after final barrier).
// Attention: 8 lanes per (row) item, 2 passes of 32 items; bitmask kv_mask.
// ---------------------------------------------------------------------------
__global__ __launch_bounds__(256, 8) void qproj_attn_kernel(
    const float* __restrict__ Aq, const u16* __restrict__ Bt,
    const float* __restrict__ bias, const u16* __restrict__ khv,
    const int* __restrict__ seg_id, const u64* __restrict__ mbits,
    u16* __restrict__ atb)
{
    __shared__ u16 smem[BM * BK + BN * BK];   // 16 KB
    u16* As = smem;
    u16* Bs = smem + BM * BK;
    u16* qt = smem;                            // 8 KB, reused after k-loop

    const int tid = threadIdx.x;
    const int w = tid >> 6, l = tid & 63;
    const int wr = w >> 1, wc = w & 1;

    const int wg = xcd_swz((int)blockIdx.x, (int)gridDim.x);
    const int bx = wg & 7;                     // 8 col blocks = 8 heads
    const int by = wg >> 3;
    const int brow = by * BM, bcol = bx * BN;
    const int K = DMODEL;

    const int srow   = l >> 3;
    const int schunk = ((l & 7) ^ srow) * 8;
    const long long ar0 = brow + w * 16 + srow;
    const long long br0 = bcol + w * 16 + srow;
    const float* gAf0 = Aq + ar0 * K + schunk;
    const float* gAf1 = gAf0 + 8 * K;
    const u16* gB0 = Bt + br0 * K + schunk;
    const u16* gB1 = gB0 + 8 * K;
    u16* lA0 = As + (w * 16) * BK;
    u16* lA1 = As + (w * 16 + 8) * BK;
    u16* lB0 = Bs + (w * 16) * BK;
    u16* lB1 = Bs + (w * 16 + 8) * BK;

    const int hi = l >> 4, lr = l & 15;
    const int r7 = lr & 7;

    f32x4 acc[2][2] = {};

    float4 p0 = *(const float4*)(gAf0), p1 = *(const float4*)(gAf0 + 4);
    float4 p2 = *(const float4*)(gAf1), p3 = *(const float4*)(gAf1 + 4);

    for (int k0 = 0; k0 < K; k0 += BK) {
        *(short8*)(lA0 + l * 8) = cvt8(p0, p1);
        *(short8*)(lA1 + l * 8) = cvt8(p2, p3);
        gload16(gB0 + k0, lB0);
        gload16(gB1 + k0, lB1);
        __syncthreads();

        if (k0 + BK < K) {
            p0 = *(const float4*)(gAf0 + k0 + BK); p1 = *(const float4*)(gAf0 + k0 + BK + 4);
            p2 = *(const float4*)(gAf1 + k0 + BK); p3 = *(const float4*)(gAf1 + k0 + BK + 4);
        }

        #pragma unroll
        for (int g2 = 0; g2 < 2; ++g2) {
            const int slot = ((g2 * 4 + hi) ^ r7) * 8;
            short8 a[2], b[2];
            #pragma unroll
            for (int m = 0; m < 2; ++m)
                a[m] = *(const short8*)&As[(wr * 32 + m * 16 + lr) * BK + slot];
            #pragma unroll
            for (int n = 0; n < 2; ++n)
                b[n] = *(const short8*)&Bs[(wc * 32 + n * 16 + lr) * BK + slot];
            #pragma unroll
            for (int m = 0; m < 2; ++m)
                #pragma unroll
                for (int n = 0; n < 2; ++n)
                    acc[m][n] = __builtin_amdgcn_mfma_f32_16x16x32_bf16(a[m], b[n], acc[m][n], 0, 0, 0);
        }
        __syncthreads();                       // last As/Bs reads complete
    }

    // stash qh tile (+bias, bf16 via cvt_pk) into chunk-swizzled qt (aliases As)
    #pragma unroll
    for (int m = 0; m < 2; ++m) {
        #pragma unroll
        for (int n = 0; n < 2; ++n) {
            const int col = wc * 32 + n * 16 + lr;
            const float bv = bias[bcol + col];
            const int row0 = wr * 32 + m * 16 + hi * 4;
            const unsigned pa = pk2(acc[m][n][0] + bv, acc[m][n][1] + bv);
            const unsigned pb = pk2(acc[m][n][2] + bv, acc[m][n][3] + bv);
            const int cslot = (col & 7);
            qt[(row0 + 0) * BN + (((col >> 3) ^ ((row0 + 0) & 7)) << 3) + cslot] = (u16)pa;
            qt[(row0 + 1) * BN + (((col >> 3) ^ ((row0 + 1) & 7)) << 3) + cslot] = (u16)(pa >> 16);
            qt[(row0 + 2) * BN + (((col >> 3) ^ ((row0 + 2) & 7)) << 3) + cslot] = (u16)pb;
            qt[(row0 + 3) * BN + (((col >> 3) ^ ((row0 + 3) & 7)) << 3) + cslot] = (u16)(pb >> 16);
        }
    }
    __syncthreads();

    // ---- attention: 8 lanes per item, 2 passes of 32 items ----
    const int dchunk = tid & 7;
    const int head = bx;
    #pragma unroll
    for (int p = 0; p < 2; ++p) {
        const int row = p * 32 + (tid >> 3);      // local row 0..63
        const long long bl = brow + row;
        const int b = (int)(bl >> 12);            // LQ = 2^12
        const int seg = seg_id[bl];
        const u16* kvb = khv + (long long)b * LKV * 1024;

        // mask window: bits for idx in [lo, seg], bit position = idx - lo
        int lo = seg - (KW - 1); if (lo < 0) lo = 0;
        const int w0 = lo >> 6, off = lo & 63;
        const u64* mb = mbits + b * 9;
        u64 wv = mb[w0] >> off;
        if (off) wv |= mb[w0 + 1] << (64 - off);

        const short8 q8 = *(const short8*)&qt[row * BN + ((dchunk ^ (row & 7)) << 3)];
        float qf[8];
        #pragma unroll
        for (int e = 0; e < 8; ++e) qf[e] = bf2f((u16)q8[e]);

        int idxs[KW];
        float sc[KW];
        #pragma unroll
        for (int j = 0; j < KW; ++j) {
            int idx = seg - j;
            if (idx < 0) idx = 0;
            idxs[j] = idx;
            const short8 k8 = *(const short8*)&kvb[(long long)idx * 1024 + head * DH + dchunk * 8];
            float d0 = 0.0f, d1 = 0.0f;
            #pragma unroll
            for (int e = 0; e < 8; e += 2) {
                d0 = fmaf(qf[e],     bf2f((u16)k8[e]),     d0);
                d1 = fmaf(qf[e + 1], bf2f((u16)k8[e + 1]), d1);
            }
            float d = d0 + d1;
            d += __shfl_xor(d, 1);
            d += __shfl_xor(d, 2);
            d += __shfl_xor(d, 4);
            float s = d * SCALE;
            if ((wv >> (idx - lo)) & 1) s = -FLT_MAX;
            sc[j] = s;
        }

        float mx = sc[0];
        #pragma unroll
        for (int j = 1; j < KW; ++j) mx = fmaxf(mx, sc[j]);
        float den = 0.0f;
        #pragma unroll
        for (int j = 0; j < KW; ++j) { sc[j] = __expf(sc[j] - mx); den += sc[j]; }
        const float inv = 1.0f / den;

        float o[8];
        #pragma unroll
        for (int e = 0; e < 8; ++e) o[e] = 0.0f;
        #pragma unroll
        for (int j = 0; j < KW; ++j) {
            const short8 v8 = *(const short8*)&kvb[(long long)idxs[j] * 1024 + DMODEL + head * DH + dchunk * 8];
            const float pj = sc[j];
            #pragma unroll
            for (int e = 0; e < 8; ++e)
                o[e] = fmaf(pj, bf2f((u16)v8[e]), o[e]);
        }

        union { unsigned u[4]; short8 s; } ov;
        #pragma unroll
        for (int e = 0; e < 4; ++e)
            ov.u[e] = pk2(o[2 * e] * inv, o[2 * e + 1] * inv);
        *(short8*)&atb[bl * DMODEL + head * DH + dchunk * 8] = ov.s;
    }
}

extern "C" void kernel_launch(void* const* d_in, const int* in_sizes, int n_in,
                              void* d_out, int out_size, void* d_ws, size_t ws_size,
                              hipStream_t stream) {
    const float*         q          = (const float*)d_in[0];
    const float*         kv_src     = (const float*)d_in[1];
    const int*           seg_id     = (const int*)d_in[2];
    const unsigned char* kv_mask    = (const unsigned char*)d_in[3];
    const unsigned char* q_pad_mask = (const unsigned char*)d_in[4];
    const float*         Wq         = (const float*)d_in[5];
    const float*         bq         = (const float*)d_in[6];
    const float*         Wk         = (const float*)d_in[7];
    const float*         bk         = (const float*)d_in[8];
    const float*         Wv         = (const float*)d_in[9];
    const float*         bv         = (const float*)d_in[10];
    const float*         Wo         = (const float*)d_in[11];
    const float*         bo         = (const float*)d_in[12];
    float* out = (float*)d_out;

    const long long MQ  = (long long)NB * LQ;    // 16384
    const long long MKV = (long long)NB * LKV;   // 2048

    char* wsb = (char*)d_ws;
    u16* Wqt  = (u16*)wsb;  wsb += DMODEL * DMODEL * 2;       // 0.5 MB
    u16* Wkvt = (u16*)wsb;  wsb += 2 * DMODEL * DMODEL * 2;   //  1 MB
    u16* Wot  = (u16*)wsb;  wsb += DMODEL * DMODEL * 2;       // 0.5 MB
    u16* khv  = (u16*)wsb;  wsb += MKV * 2 * DMODEL * 2;      //  4 MB
    u16* atb  = (u16*)wsb;  wsb += MQ  * DMODEL * 2;          // 16 MB
    u64* mbits = (u64*)wsb; wsb += NB * 9 * 8;                // 288 B

    dim3 blk(256);

    transpose4_kernel<<<dim3(DMODEL / 32, DMODEL / 32, 4), blk, 0, stream>>>(
        Wq, Wk, Wv, Wo, Wqt, Wkvt, Wot);

    // fused K+V projection (fp32 A) + kv_mask bitpack; 512 blocks, cshift=4
    gemm64_kernel<1, 0, 1><<<dim3((unsigned)((2 * DMODEL / BN) * (MKV / BM))), blk, 0, stream>>>(
        kv_src, Wkvt, bk, bv, DMODEL, khv, 2 * DMODEL, DMODEL, 4, nullptr, kv_mask, mbits);

    // fused Q projection (fp32 A) + windowed attention -> atb; 2048 blocks
    qproj_attn_kernel<<<dim3((unsigned)((DMODEL / BN) * (MQ / BM))), blk, 0, stream>>>(
        q, Wqt, bq, khv, seg_id, mbits, atb);

    // output projection + pad-mask zeroing (fp32 out); 2048 blocks, cshift=3
    gemm64_kernel<0, 1, 0><<<dim3((unsigned)((DMODEL / BN) * (MQ / BM))), blk, 0, stream>>>(
        atb, Wot, bo, bo, DMODEL, out, DMODEL, DMODEL, 3, q_pad_mask, nullptr, nullptr);
}